// Round 1
// baseline (996.733 us; speedup 1.0000x reference)
//
#include <hip/hip_runtime.h>
#include <math.h>

// Problem constants (from reference): B=16, C=512, H=W=32, HW=1024.
//   X[b]  (C x HW)  = n1[b] (C x HW) @ W_c^T (W_c is HW x HW, row-major)   [NT]
//   E[b]  (HW x HW) = X[b]^T @ n2[b]                                       [TN]
//   A[b]  = softmax rows of E[b]   (in-place)
//   out[b](C x HW)  = n2[b] @ A[b]                                         [NN]
//
// Round 0: pure fp32 (softmax logits are too argmax-sensitive for naive bf16;
// split-bf16 MFMA is the planned later optimization).

#define TM 64
#define TN 64
#define TK 16

// C[M,N] = A[M,K] * B[N,K]^T   (c[m,n] = sum_k A[m*K+k]*B[n*K+k])
__global__ __launch_bounds__(256) void gemm_nt(const float* __restrict__ A,
                                               const float* __restrict__ B,
                                               float* __restrict__ C,
                                               int M, int N, int K,
                                               long sA, long sB, long sC) {
    int b = blockIdx.z;
    A += (long)b * sA; B += (long)b * sB; C += (long)b * sC;
    __shared__ float As[TK][TM + 1];
    __shared__ float Bs[TK][TN + 1];
    const int m0 = blockIdx.y * TM, n0 = blockIdx.x * TN;
    const int tid = threadIdx.x;
    const int tx = tid & 15, ty = tid >> 4;
    float acc[4][4] = {};
    for (int k0 = 0; k0 < K; k0 += TK) {
        const int kk = tid & 15, i = tid >> 4;  // i in 0..15
#pragma unroll
        for (int s = 0; s < 4; ++s) {
            As[kk][i + 16 * s] = A[(long)(m0 + i + 16 * s) * K + (k0 + kk)];
            Bs[kk][i + 16 * s] = B[(long)(n0 + i + 16 * s) * K + (k0 + kk)];
        }
        __syncthreads();
#pragma unroll
        for (int k = 0; k < TK; ++k) {
            float a[4], bb[4];
#pragma unroll
            for (int u = 0; u < 4; ++u) a[u] = As[k][ty + 16 * u];
#pragma unroll
            for (int v = 0; v < 4; ++v) bb[v] = Bs[k][tx + 16 * v];
#pragma unroll
            for (int u = 0; u < 4; ++u)
#pragma unroll
                for (int v = 0; v < 4; ++v) acc[u][v] += a[u] * bb[v];
        }
        __syncthreads();
    }
#pragma unroll
    for (int u = 0; u < 4; ++u)
#pragma unroll
        for (int v = 0; v < 4; ++v)
            C[(long)(m0 + ty + 16 * u) * N + (n0 + tx + 16 * v)] = acc[u][v];
}

// C[M,N] = A^T * B with A[K,M], B[K,N] row-major (c[m,n] = sum_k A[k*M+m]*B[k*N+n])
__global__ __launch_bounds__(256) void gemm_tn(const float* __restrict__ A,
                                               const float* __restrict__ B,
                                               float* __restrict__ C,
                                               int M, int N, int K,
                                               long sA, long sB, long sC) {
    int b = blockIdx.z;
    A += (long)b * sA; B += (long)b * sB; C += (long)b * sC;
    __shared__ float As[TK][TM + 1];
    __shared__ float Bs[TK][TN + 1];
    const int m0 = blockIdx.y * TM, n0 = blockIdx.x * TN;
    const int tid = threadIdx.x;
    const int tx = tid & 15, ty = tid >> 4;
    float acc[4][4] = {};
    for (int k0 = 0; k0 < K; k0 += TK) {
        const int i = tid & 63, kq = tid >> 6;  // kq in 0..3
#pragma unroll
        for (int s = 0; s < 4; ++s) {
            const int kk = kq * 4 + s;
            As[kk][i] = A[(long)(k0 + kk) * M + (m0 + i)];
            Bs[kk][i] = B[(long)(k0 + kk) * N + (n0 + i)];
        }
        __syncthreads();
#pragma unroll
        for (int k = 0; k < TK; ++k) {
            float a[4], bb[4];
#pragma unroll
            for (int u = 0; u < 4; ++u) a[u] = As[k][ty + 16 * u];
#pragma unroll
            for (int v = 0; v < 4; ++v) bb[v] = Bs[k][tx + 16 * v];
#pragma unroll
            for (int u = 0; u < 4; ++u)
#pragma unroll
                for (int v = 0; v < 4; ++v) acc[u][v] += a[u] * bb[v];
        }
        __syncthreads();
    }
#pragma unroll
    for (int u = 0; u < 4; ++u)
#pragma unroll
        for (int v = 0; v < 4; ++v)
            C[(long)(m0 + ty + 16 * u) * N + (n0 + tx + 16 * v)] = acc[u][v];
}

// C[M,N] = A * B with A[M,K], B[K,N] row-major
__global__ __launch_bounds__(256) void gemm_nn(const float* __restrict__ A,
                                               const float* __restrict__ B,
                                               float* __restrict__ C,
                                               int M, int N, int K,
                                               long sA, long sB, long sC) {
    int b = blockIdx.z;
    A += (long)b * sA; B += (long)b * sB; C += (long)b * sC;
    __shared__ float As[TK][TM + 1];
    __shared__ float Bs[TK][TN + 1];
    const int m0 = blockIdx.y * TM, n0 = blockIdx.x * TN;
    const int tid = threadIdx.x;
    const int tx = tid & 15, ty = tid >> 4;
    float acc[4][4] = {};
    for (int k0 = 0; k0 < K; k0 += TK) {
        {
            const int kk = tid & 15, i = tid >> 4;
#pragma unroll
            for (int s = 0; s < 4; ++s)
                As[kk][i + 16 * s] = A[(long)(m0 + i + 16 * s) * K + (k0 + kk)];
            const int j = tid & 63, kq = tid >> 6;
#pragma unroll
            for (int s = 0; s < 4; ++s)
                Bs[kq * 4 + s][j] = B[(long)(k0 + kq * 4 + s) * N + (n0 + j)];
        }
        __syncthreads();
#pragma unroll
        for (int k = 0; k < TK; ++k) {
            float a[4], bb[4];
#pragma unroll
            for (int u = 0; u < 4; ++u) a[u] = As[k][ty + 16 * u];
#pragma unroll
            for (int v = 0; v < 4; ++v) bb[v] = Bs[k][tx + 16 * v];
#pragma unroll
            for (int u = 0; u < 4; ++u)
#pragma unroll
                for (int v = 0; v < 4; ++v) acc[u][v] += a[u] * bb[v];
        }
        __syncthreads();
    }
#pragma unroll
    for (int u = 0; u < 4; ++u)
#pragma unroll
        for (int v = 0; v < 4; ++v)
            C[(long)(m0 + ty + 16 * u) * N + (n0 + tx + 16 * v)] = acc[u][v];
}

// In-place row softmax over rows of length 1024. One 256-thread block per row.
__global__ __launch_bounds__(256) void softmax_rows(float* __restrict__ E) {
    const int N = 1024;
    float* p = E + (long)blockIdx.x * N;
    const int tid = threadIdx.x;
    float v[4];
#pragma unroll
    for (int s = 0; s < 4; ++s) v[s] = p[tid + 256 * s];
    float lmax = fmaxf(fmaxf(v[0], v[1]), fmaxf(v[2], v[3]));
#pragma unroll
    for (int off = 32; off; off >>= 1) lmax = fmaxf(lmax, __shfl_down(lmax, off, 64));
    __shared__ float sm[4];
    __shared__ float ss[4];
    const int wave = tid >> 6, lane = tid & 63;
    if (lane == 0) sm[wave] = lmax;
    __syncthreads();
    const float rmax = fmaxf(fmaxf(sm[0], sm[1]), fmaxf(sm[2], sm[3]));
    float lsum = 0.f;
#pragma unroll
    for (int s = 0; s < 4; ++s) {
        v[s] = __expf(v[s] - rmax);
        lsum += v[s];
    }
#pragma unroll
    for (int off = 32; off; off >>= 1) lsum += __shfl_down(lsum, off, 64);
    if (lane == 0) ss[wave] = lsum;
    __syncthreads();
    const float inv = 1.0f / (ss[0] + ss[1] + ss[2] + ss[3]);
#pragma unroll
    for (int s = 0; s < 4; ++s) p[tid + 256 * s] = v[s] * inv;
}

extern "C" void kernel_launch(void* const* d_in, const int* in_sizes, int n_in,
                              void* d_out, int out_size, void* d_ws, size_t ws_size,
                              hipStream_t stream) {
    const int B = 16, C = 512, HW = 1024;
    const float* n1 = (const float*)d_in[0];
    const float* n2 = (const float*)d_in[1];
    const float* Wc = (const float*)d_in[2];
    float* out = (float*)d_out;

    float* X = (float*)d_ws;                                   // B*C*HW fp32 = 33.5 MB
    float* E = (float*)((char*)d_ws + (size_t)B * C * HW * 4); // B*HW*HW fp32 = 67 MB

    const long sN = (long)C * HW;   // per-batch stride of n1/n2/X/out
    const long sE = (long)HW * HW;  // per-batch stride of E

    dim3 blk(256);
    // X[b] = n1[b] @ Wc^T   (M=C, N=HW, K=HW; B batched, Wc shared)
    gemm_nt<<<dim3(HW / TN, C / TM, B), blk, 0, stream>>>(n1, Wc, X, C, HW, HW, sN, 0, sN);
    // E[b] = X[b]^T @ n2[b] (M=HW, N=HW, K=C)
    gemm_tn<<<dim3(HW / TN, HW / TM, B), blk, 0, stream>>>(X, n2, E, HW, HW, C, sN, sN, sE);
    // A[b] = softmax_rows(E[b])  in place
    softmax_rows<<<dim3(B * HW), blk, 0, stream>>>(E);
    // out[b] = n2[b] @ A[b]  (M=C, N=HW, K=HW)
    gemm_nn<<<dim3(HW / TN, C / TM, B), blk, 0, stream>>>(n2, E, out, C, HW, HW, sN, sE, sN);
}

// Round 2
// 383.904 us; speedup vs baseline: 2.5963x; 2.5963x over previous
//
#include <hip/hip_runtime.h>
#include <math.h>

// B=16, C=512, HW=1024.
//   X[b]  (C x HW)  = n1[b] @ W_c^T            [NT, split-bf16 MFMA]
//   E[b]  (HW x HW) = X[b]^T @ n2[b]           [TN, split-bf16 MFMA]
//   A[b]  = softmax rows of E[b] -> bf16 (stored over dead X region)
//   out[b](C x HW)  = n2[b] @ A[b]             [NN, plain-bf16 MFMA]
//
// Split bf16: x = hi + lo (each bf16); A*B ~= Ah*Bh + Ah*Bl + Al*Bh (3 MFMAs),
// giving ~1e-3 logit accuracy (vs ~0.09 naive bf16 — softmax rows are near
// one-hot with top-2 gaps sometimes <1, naive bf16 risks the 0.2125 absmax).

typedef __bf16 bf16x8 __attribute__((ext_vector_type(8)));
typedef float f32x4 __attribute__((ext_vector_type(4)));
typedef unsigned short u16x8 __attribute__((ext_vector_type(8)));

#define LDK 40  // padded LDS row (elements) for 32-k tiles: 80 B -> b128 reads 2-way (free)

__device__ __forceinline__ unsigned short f2bf(float f) {
    unsigned int u = __float_as_uint(f);
    u += 0x7fff + ((u >> 16) & 1);  // round-to-nearest-even
    return (unsigned short)(u >> 16);
}
__device__ __forceinline__ float bf2f(unsigned short s) {
    return __uint_as_float(((unsigned int)s) << 16);
}

// ---------------------------------------------------------------------------
// C[M,N] = A[M,K] * B[N,K]^T, split bf16. Both operands natural (k contiguous).
__global__ __launch_bounds__(256) void gemm_nt_split(
    const float* __restrict__ A, const float* __restrict__ B, float* __restrict__ C,
    int M, int N, int K, long sA, long sB, long sC) {
    const int b = blockIdx.z;
    A += (long)b * sA; B += (long)b * sB; C += (long)b * sC;
    __shared__ __attribute__((aligned(16))) unsigned short Ah[64][LDK], Al[64][LDK],
                                                           Bh[64][LDK], Bl[64][LDK];
    const int m0 = blockIdx.y * 64, n0 = blockIdx.x * 64;
    const int tid = threadIdx.x, lane = tid & 63, wave = tid >> 6;
    const int wm = (wave & 1) * 32, wn = (wave >> 1) * 32;
    const int col = lane & 15, quad = lane >> 4;
    const int sm = tid >> 2, skg = (tid & 3) * 8;  // staging: row, k-offset (8 floats)

    f32x4 acc[2][2] = {};
    for (int k0 = 0; k0 < K; k0 += 32) {
        const float* ga = A + (long)(m0 + sm) * K + k0 + skg;
        const float* gb = B + (long)(n0 + sm) * K + k0 + skg;
        u16x8 ah, al, bh, bl;
#pragma unroll
        for (int j = 0; j < 8; ++j) {
            float x = ga[j];
            unsigned short h = f2bf(x);
            ah[j] = h; al[j] = f2bf(x - bf2f(h));
            float y = gb[j];
            unsigned short h2 = f2bf(y);
            bh[j] = h2; bl[j] = f2bf(y - bf2f(h2));
        }
        *(u16x8*)&Ah[sm][skg] = ah; *(u16x8*)&Al[sm][skg] = al;
        *(u16x8*)&Bh[sm][skg] = bh; *(u16x8*)&Bl[sm][skg] = bl;
        __syncthreads();
        bf16x8 fah[2], fal[2], fbh[2], fbl[2];
#pragma unroll
        for (int u = 0; u < 2; ++u) {
            fah[u] = *(const bf16x8*)&Ah[wm + u * 16 + col][quad * 8];
            fal[u] = *(const bf16x8*)&Al[wm + u * 16 + col][quad * 8];
            fbh[u] = *(const bf16x8*)&Bh[wn + u * 16 + col][quad * 8];
            fbl[u] = *(const bf16x8*)&Bl[wn + u * 16 + col][quad * 8];
        }
#pragma unroll
        for (int u = 0; u < 2; ++u)
#pragma unroll
            for (int v = 0; v < 2; ++v) {
                acc[u][v] = __builtin_amdgcn_mfma_f32_16x16x32_bf16(fah[u], fbh[v], acc[u][v], 0, 0, 0);
                acc[u][v] = __builtin_amdgcn_mfma_f32_16x16x32_bf16(fah[u], fbl[v], acc[u][v], 0, 0, 0);
                acc[u][v] = __builtin_amdgcn_mfma_f32_16x16x32_bf16(fal[u], fbh[v], acc[u][v], 0, 0, 0);
            }
        __syncthreads();
    }
#pragma unroll
    for (int u = 0; u < 2; ++u)
#pragma unroll
        for (int v = 0; v < 2; ++v)
#pragma unroll
            for (int r = 0; r < 4; ++r)
                C[(long)(m0 + wm + u * 16 + quad * 4 + r) * N + n0 + wn + v * 16 + col] = acc[u][v][r];
}

// ---------------------------------------------------------------------------
// C[M,N] = A^T * B, A[K,M], B[K,N] row-major. Split bf16. Both operands need a
// transposed LDS store; m=(t&7)+8i mapping keeps ds_write_b16 banks <=2-way.
__global__ __launch_bounds__(256) void gemm_tn_split(
    const float* __restrict__ A, const float* __restrict__ B, float* __restrict__ C,
    int M, int N, int K, long sA, long sB, long sC) {
    const int b = blockIdx.z;
    A += (long)b * sA; B += (long)b * sB; C += (long)b * sC;
    __shared__ __attribute__((aligned(16))) unsigned short Ah[64][LDK], Al[64][LDK],
                                                           Bh[64][LDK], Bl[64][LDK];
    const int m0 = blockIdx.y * 64, n0 = blockIdx.x * 64;
    const int tid = threadIdx.x, lane = tid & 63, wave = tid >> 6;
    const int wm = (wave & 1) * 32, wn = (wave >> 1) * 32;
    const int col = lane & 15, quad = lane >> 4;
    const int skk = tid >> 3, smc = tid & 7;  // staging: k row, m base

    f32x4 acc[2][2] = {};
    for (int k0 = 0; k0 < K; k0 += 32) {
        const float* ga = A + (long)(k0 + skk) * M + m0 + smc;
        const float* gb = B + (long)(k0 + skk) * N + n0 + smc;
#pragma unroll
        for (int i = 0; i < 8; ++i) {
            float x = ga[8 * i];
            unsigned short h = f2bf(x);
            Ah[smc + 8 * i][skk] = h;
            Al[smc + 8 * i][skk] = f2bf(x - bf2f(h));
            float y = gb[8 * i];
            unsigned short h2 = f2bf(y);
            Bh[smc + 8 * i][skk] = h2;
            Bl[smc + 8 * i][skk] = f2bf(y - bf2f(h2));
        }
        __syncthreads();
        bf16x8 fah[2], fal[2], fbh[2], fbl[2];
#pragma unroll
        for (int u = 0; u < 2; ++u) {
            fah[u] = *(const bf16x8*)&Ah[wm + u * 16 + col][quad * 8];
            fal[u] = *(const bf16x8*)&Al[wm + u * 16 + col][quad * 8];
            fbh[u] = *(const bf16x8*)&Bh[wn + u * 16 + col][quad * 8];
            fbl[u] = *(const bf16x8*)&Bl[wn + u * 16 + col][quad * 8];
        }
#pragma unroll
        for (int u = 0; u < 2; ++u)
#pragma unroll
            for (int v = 0; v < 2; ++v) {
                acc[u][v] = __builtin_amdgcn_mfma_f32_16x16x32_bf16(fah[u], fbh[v], acc[u][v], 0, 0, 0);
                acc[u][v] = __builtin_amdgcn_mfma_f32_16x16x32_bf16(fah[u], fbl[v], acc[u][v], 0, 0, 0);
                acc[u][v] = __builtin_amdgcn_mfma_f32_16x16x32_bf16(fal[u], fbh[v], acc[u][v], 0, 0, 0);
            }
        __syncthreads();
    }
#pragma unroll
    for (int u = 0; u < 2; ++u)
#pragma unroll
        for (int v = 0; v < 2; ++v)
#pragma unroll
            for (int r = 0; r < 4; ++r)
                C[(long)(m0 + wm + u * 16 + quad * 4 + r) * N + n0 + wn + v * 16 + col] = acc[u][v][r];
}

// ---------------------------------------------------------------------------
// C[M,N] = A[M,K](fp32) * Bq[K,N](bf16), plain bf16 MFMA.
__global__ __launch_bounds__(256) void gemm_nn_bf16(
    const float* __restrict__ A, const unsigned short* __restrict__ Bq, float* __restrict__ C,
    int M, int N, int K, long sA, long sB, long sC) {
    const int b = blockIdx.z;
    A += (long)b * sA; Bq += (long)b * sB; C += (long)b * sC;
    __shared__ __attribute__((aligned(16))) unsigned short Ah[64][LDK], Bh[64][LDK];
    const int m0 = blockIdx.y * 64, n0 = blockIdx.x * 64;
    const int tid = threadIdx.x, lane = tid & 63, wave = tid >> 6;
    const int wm = (wave & 1) * 32, wn = (wave >> 1) * 32;
    const int col = lane & 15, quad = lane >> 4;
    const int sm = tid >> 2, skg = (tid & 3) * 8;  // A staging (natural)
    const int skk = tid >> 3, smc = tid & 7;       // B staging (transposed)

    f32x4 acc[2][2] = {};
    for (int k0 = 0; k0 < K; k0 += 32) {
        const float* ga = A + (long)(m0 + sm) * K + k0 + skg;
        u16x8 ah;
#pragma unroll
        for (int j = 0; j < 8; ++j) ah[j] = f2bf(ga[j]);
        *(u16x8*)&Ah[sm][skg] = ah;
        const unsigned short* gb = Bq + (long)(k0 + skk) * N + n0 + smc;
#pragma unroll
        for (int i = 0; i < 8; ++i) Bh[smc + 8 * i][skk] = gb[8 * i];
        __syncthreads();
        bf16x8 fa[2], fb[2];
#pragma unroll
        for (int u = 0; u < 2; ++u) {
            fa[u] = *(const bf16x8*)&Ah[wm + u * 16 + col][quad * 8];
            fb[u] = *(const bf16x8*)&Bh[wn + u * 16 + col][quad * 8];
        }
#pragma unroll
        for (int u = 0; u < 2; ++u)
#pragma unroll
            for (int v = 0; v < 2; ++v)
                acc[u][v] = __builtin_amdgcn_mfma_f32_16x16x32_bf16(fa[u], fb[v], acc[u][v], 0, 0, 0);
        __syncthreads();
    }
#pragma unroll
    for (int u = 0; u < 2; ++u)
#pragma unroll
        for (int v = 0; v < 2; ++v)
#pragma unroll
            for (int r = 0; r < 4; ++r)
                C[(long)(m0 + wm + u * 16 + quad * 4 + r) * N + n0 + wn + v * 16 + col] = acc[u][v][r];
}

// ---------------------------------------------------------------------------
// Row softmax over rows of 1024 fp32; writes bf16. One 256-thread block per row.
__global__ __launch_bounds__(256) void softmax_rows_bf16(const float* __restrict__ E,
                                                         unsigned short* __restrict__ O) {
    const int N = 1024;
    const float* p = E + (long)blockIdx.x * N;
    unsigned short* q = O + (long)blockIdx.x * N;
    const int tid = threadIdx.x;
    float v[4];
#pragma unroll
    for (int s = 0; s < 4; ++s) v[s] = p[tid + 256 * s];
    float lmax = fmaxf(fmaxf(v[0], v[1]), fmaxf(v[2], v[3]));
#pragma unroll
    for (int off = 32; off; off >>= 1) lmax = fmaxf(lmax, __shfl_down(lmax, off, 64));
    __shared__ float sm[4], ss[4];
    const int wave = tid >> 6, lane = tid & 63;
    if (lane == 0) sm[wave] = lmax;
    __syncthreads();
    const float rmax = fmaxf(fmaxf(sm[0], sm[1]), fmaxf(sm[2], sm[3]));
    float lsum = 0.f;
#pragma unroll
    for (int s = 0; s < 4; ++s) {
        v[s] = __expf(v[s] - rmax);
        lsum += v[s];
    }
#pragma unroll
    for (int off = 32; off; off >>= 1) lsum += __shfl_down(lsum, off, 64);
    if (lane == 0) ss[wave] = lsum;
    __syncthreads();
    const float inv = 1.0f / (ss[0] + ss[1] + ss[2] + ss[3]);
#pragma unroll
    for (int s = 0; s < 4; ++s) q[tid + 256 * s] = f2bf(v[s] * inv);
}

extern "C" void kernel_launch(void* const* d_in, const int* in_sizes, int n_in,
                              void* d_out, int out_size, void* d_ws, size_t ws_size,
                              hipStream_t stream) {
    const int B = 16, C = 512, HW = 1024;
    const float* n1 = (const float*)d_in[0];
    const float* n2 = (const float*)d_in[1];
    const float* Wc = (const float*)d_in[2];
    float* out = (float*)d_out;

    float* X = (float*)d_ws;                                    // 33.5 MB fp32
    float* E = (float*)((char*)d_ws + (size_t)B * C * HW * 4);  // 67 MB fp32
    unsigned short* Asm = (unsigned short*)d_ws;  // bf16, overwrites dead X after gemm2

    const long sN = (long)C * HW;   // n1/n2/X/out batch stride
    const long sE = (long)HW * HW;  // E/Asm batch stride

    dim3 blk(256);
    // X[b] = n1[b] @ Wc^T  (M=512, N=1024, K=1024)
    gemm_nt_split<<<dim3(HW / 64, C / 64, B), blk, 0, stream>>>(n1, Wc, X, C, HW, HW, sN, 0, sN);
    // E[b] = X[b]^T @ n2[b]  (M=1024, N=1024, K=512)
    gemm_tn_split<<<dim3(HW / 64, HW / 64, B), blk, 0, stream>>>(X, n2, E, HW, HW, C, sN, sN, sE);
    // Asm[b] = softmax rows of E[b]  (bf16)
    softmax_rows_bf16<<<dim3(B * HW), blk, 0, stream>>>(E, Asm);
    // out[b] = n2[b] @ Asm[b]  (M=512, N=1024, K=1024)
    gemm_nn_bf16<<<dim3(HW / 64, C / 64, B), blk, 0, stream>>>(n2, Asm, out, C, HW, HW, sN, sE, sN);
}

// Round 3
// 252.948 us; speedup vs baseline: 3.9405x; 1.5177x over previous
//
#include <hip/hip_runtime.h>
#include <math.h>

// B=16, C=512, HW=1024.  Chain (per batch):
//   X  (C x HW)  = n1 @ W_c^T
//   E  (HW x HW) = X^T @ n2
//   A  = row-softmax(E)
//   out(C x HW)  = n2 @ A
//
// Round 3: everything fp16 MFMA (plain, 1 MFMA per tile — fp16's 11-bit
// mantissa gives ~0.01 logit error, vs 3-MFMA bf16 split last round).
// All GEMMs are NT (both operands k-contiguous) in the m97 structure:
// 128x128 tile, BK=32, global_load_lds width=16, no staging VALU.
// Layout plumbing: pre-pass converts n1,Wc -> fp16 and n2 -> fp16-transposed;
// GEMM1 writes X^T via LDS-transpose epilogue; E is fp16, softmax in-place;
// fp16 transpose produces A^T for GEMM3.
//
// Workspace (96 MiB, proven size):
//   [0,16M):   n2t  f16 [b][h][c]
//   [16,32M):  Xt   f16 [b][o][c]
//   [32,64M):  E    f16 [b][o][h]   (softmax in-place)
//   [64,96M):  n1f(16M)+Wf(2M)  then  At f16 [b][j][k]  (aliased, dead by then)

typedef _Float16 f16;
typedef _Float16 f16x8 __attribute__((ext_vector_type(8)));
typedef _Float16 f16x4 __attribute__((ext_vector_type(4)));
typedef float f32x4 __attribute__((ext_vector_type(4)));

__device__ __forceinline__ void glds16(const void* g, void* l) {
    __builtin_amdgcn_global_load_lds((const __attribute__((address_space(1))) void*)g,
                                     (__attribute__((address_space(3))) void*)l, 16, 0, 0);
}

// ---------------------------------------------------------------------------
// fp32 -> fp16 elementwise, 8/thread.
__global__ __launch_bounds__(256) void cvt_f32_f16(const float* __restrict__ s,
                                                   f16* __restrict__ d) {
    size_t i = ((size_t)blockIdx.x * 256 + threadIdx.x) * 8;
    f32x4 a = *(const f32x4*)(s + i);
    f32x4 b = *(const f32x4*)(s + i + 4);
    f16x8 o;
    o[0] = (f16)a[0]; o[1] = (f16)a[1]; o[2] = (f16)a[2]; o[3] = (f16)a[3];
    o[4] = (f16)b[0]; o[5] = (f16)b[1]; o[6] = (f16)b[2]; o[7] = (f16)b[3];
    *(f16x8*)(d + i) = o;
}

// ---------------------------------------------------------------------------
// n2 [b][512][1024] f32  ->  n2t [b][1024][512] f16 (transpose+convert)
__global__ __launch_bounds__(256) void tr_f32_f16(const float* __restrict__ S,
                                                  f16* __restrict__ D) {
    const int b = blockIdx.z;
    S += (size_t)b * 512 * 1024;
    D += (size_t)b * 1024 * 512;
    __shared__ f16 Ts[64 * 72];
    const int r0 = blockIdx.y * 64, c0 = blockIdx.x * 64;
    const int tid = threadIdx.x;
    const int rr = tid >> 3, cc8 = (tid & 7) * 8;
#pragma unroll
    for (int h = 0; h < 2; ++h) {
        const float* s = S + (size_t)(r0 + rr + 32 * h) * 1024 + c0 + cc8;
        f32x4 a = *(const f32x4*)s, bq = *(const f32x4*)(s + 4);
        f16x8 o;
        o[0] = (f16)a[0]; o[1] = (f16)a[1]; o[2] = (f16)a[2]; o[3] = (f16)a[3];
        o[4] = (f16)bq[0]; o[5] = (f16)bq[1]; o[6] = (f16)bq[2]; o[7] = (f16)bq[3];
        *(f16x8*)&Ts[(rr + 32 * h) * 72 + cc8] = o;
    }
    __syncthreads();
    const int j = tid >> 2, k16 = (tid & 3) * 16;
    f16* d = D + (size_t)(c0 + j) * 512 + r0 + k16;
    f16x8 o0, o1;
#pragma unroll
    for (int i = 0; i < 8; ++i) {
        o0[i] = Ts[(k16 + i) * 72 + j];
        o1[i] = Ts[(k16 + 8 + i) * 72 + j];
    }
    *(f16x8*)d = o0;
    *(f16x8*)(d + 8) = o1;
}

// ---------------------------------------------------------------------------
// A [b][1024][1024] f16 -> At [b][1024][1024] f16 transposed
__global__ __launch_bounds__(256) void tr_f16(const f16* __restrict__ S,
                                              f16* __restrict__ D) {
    const int b = blockIdx.z;
    S += (size_t)b * 1024 * 1024;
    D += (size_t)b * 1024 * 1024;
    __shared__ f16 Ts[64 * 72];
    const int r0 = blockIdx.y * 64, c0 = blockIdx.x * 64;
    const int tid = threadIdx.x;
    const int rr = tid >> 3, cc8 = (tid & 7) * 8;
#pragma unroll
    for (int h = 0; h < 2; ++h)
        *(f16x8*)&Ts[(rr + 32 * h) * 72 + cc8] =
            *(const f16x8*)(S + (size_t)(r0 + rr + 32 * h) * 1024 + c0 + cc8);
    __syncthreads();
    const int j = tid >> 2, k16 = (tid & 3) * 16;
    f16* d = D + (size_t)(c0 + j) * 1024 + r0 + k16;
    f16x8 o0, o1;
#pragma unroll
    for (int i = 0; i < 8; ++i) {
        o0[i] = Ts[(k16 + i) * 72 + j];
        o1[i] = Ts[(k16 + 8 + i) * 72 + j];
    }
    *(f16x8*)d = o0;
    *(f16x8*)(d + 8) = o1;
}

// ---------------------------------------------------------------------------
// GEMM1: Xt[b][o][c] = (n1f[b] @ Wf^T)^T.  A=n1f (M=512,K=1024), B=Wf (N=1024).
__global__ __launch_bounds__(256) void gemm1_nt_xt(const f16* __restrict__ A,
                                                   const f16* __restrict__ Bw,
                                                   f16* __restrict__ Xt) {
    const int M = 512, K = 1024;
    const int b = blockIdx.z;
    A += (size_t)b * M * K;
    Xt += (size_t)b * 1024 * M;
    __shared__ __attribute__((aligned(16))) f16 As[128 * 32], Bs[128 * 32];
    __shared__ __attribute__((aligned(16))) f16 Tt[128 * 136];
    const int tid = threadIdx.x, lane = tid & 63, wave = tid >> 6;
    const int m0 = blockIdx.y * 128, n0 = blockIdx.x * 128;
    const int col = lane & 15, quad = lane >> 4;
    const int wm = (wave & 1) * 64, wn = (wave >> 1) * 64;
    const int off0 = wave * 2048 + lane * 16, off1 = off0 + 1024;
    const char* gA0 = (const char*)(A + (size_t)(m0 + (off0 >> 6)) * K) + (off0 & 63);
    const char* gA1 = (const char*)(A + (size_t)(m0 + (off1 >> 6)) * K) + (off1 & 63);
    const char* gB0 = (const char*)(Bw + (size_t)(n0 + (off0 >> 6)) * K) + (off0 & 63);
    const char* gB1 = (const char*)(Bw + (size_t)(n0 + (off1 >> 6)) * K) + (off1 & 63);
    char* lA = (char*)As + wave * 2048;
    char* lB = (char*)Bs + wave * 2048;

    f32x4 acc[4][4] = {};
    for (int kb = 0; kb < K * 2; kb += 64) {
        glds16(gA0 + kb, lA);
        glds16(gA1 + kb, lA + 1024);
        glds16(gB0 + kb, lB);
        glds16(gB1 + kb, lB + 1024);
        __syncthreads();
        f16x8 fa[4], fb[4];
#pragma unroll
        for (int u = 0; u < 4; ++u) {
            fa[u] = *(const f16x8*)&As[(wm + u * 16 + col) * 32 + quad * 8];
            fb[u] = *(const f16x8*)&Bs[(wn + u * 16 + col) * 32 + quad * 8];
        }
#pragma unroll
        for (int u = 0; u < 4; ++u)
#pragma unroll
            for (int v = 0; v < 4; ++v)
                acc[u][v] = __builtin_amdgcn_mfma_f32_16x16x32_f16(fa[u], fb[v], acc[u][v], 0, 0, 0);
        __syncthreads();
    }
    // Transposed epilogue: Tt[n][m] (pad 136), then coalesced rows of Xt.
#pragma unroll
    for (int u = 0; u < 4; ++u)
#pragma unroll
        for (int v = 0; v < 4; ++v) {
            f16x4 p;
#pragma unroll
            for (int r = 0; r < 4; ++r) p[r] = (f16)acc[u][v][r];
            *(f16x4*)&Tt[(wn + v * 16 + col) * 136 + wm + u * 16 + quad * 4] = p;
        }
    __syncthreads();
    const int j = tid >> 1, half = (tid & 1) * 64;
    f16* dst = Xt + (size_t)(n0 + j) * M + m0 + half;
#pragma unroll
    for (int c8 = 0; c8 < 64; c8 += 8)
        *(f16x8*)(dst + c8) = *(const f16x8*)&Tt[j * 136 + half + c8];
}

// ---------------------------------------------------------------------------
// GEMM2: E[b][o][h] (f16) = Xt[b] @ n2t[b]^T.  M=N=1024, K=512.
__global__ __launch_bounds__(256) void gemm2_nt_e(const f16* __restrict__ A,
                                                  const f16* __restrict__ B,
                                                  f16* __restrict__ E) {
    const int K = 512;
    const int b = blockIdx.z;
    A += (size_t)b * 1024 * K;
    B += (size_t)b * 1024 * K;
    E += (size_t)b * 1024 * 1024;
    __shared__ __attribute__((aligned(16))) f16 As[128 * 32], Bs[128 * 32];
    const int tid = threadIdx.x, lane = tid & 63, wave = tid >> 6;
    const int m0 = blockIdx.y * 128, n0 = blockIdx.x * 128;
    const int col = lane & 15, quad = lane >> 4;
    const int wm = (wave & 1) * 64, wn = (wave >> 1) * 64;
    const int off0 = wave * 2048 + lane * 16, off1 = off0 + 1024;
    const char* gA0 = (const char*)(A + (size_t)(m0 + (off0 >> 6)) * K) + (off0 & 63);
    const char* gA1 = (const char*)(A + (size_t)(m0 + (off1 >> 6)) * K) + (off1 & 63);
    const char* gB0 = (const char*)(B + (size_t)(n0 + (off0 >> 6)) * K) + (off0 & 63);
    const char* gB1 = (const char*)(B + (size_t)(n0 + (off1 >> 6)) * K) + (off1 & 63);
    char* lA = (char*)As + wave * 2048;
    char* lB = (char*)Bs + wave * 2048;

    f32x4 acc[4][4] = {};
    for (int kb = 0; kb < K * 2; kb += 64) {
        glds16(gA0 + kb, lA);
        glds16(gA1 + kb, lA + 1024);
        glds16(gB0 + kb, lB);
        glds16(gB1 + kb, lB + 1024);
        __syncthreads();
        f16x8 fa[4], fb[4];
#pragma unroll
        for (int u = 0; u < 4; ++u) {
            fa[u] = *(const f16x8*)&As[(wm + u * 16 + col) * 32 + quad * 8];
            fb[u] = *(const f16x8*)&Bs[(wn + u * 16 + col) * 32 + quad * 8];
        }
#pragma unroll
        for (int u = 0; u < 4; ++u)
#pragma unroll
            for (int v = 0; v < 4; ++v)
                acc[u][v] = __builtin_amdgcn_mfma_f32_16x16x32_f16(fa[u], fb[v], acc[u][v], 0, 0, 0);
        __syncthreads();
    }
#pragma unroll
    for (int u = 0; u < 4; ++u)
#pragma unroll
        for (int v = 0; v < 4; ++v)
#pragma unroll
            for (int r = 0; r < 4; ++r)
                E[(size_t)(m0 + wm + u * 16 + quad * 4 + r) * 1024 + n0 + wn + v * 16 + col] =
                    (f16)acc[u][v][r];
}

// ---------------------------------------------------------------------------
// GEMM3: out[b][c][j] (f32) = n2[b](f32) @ A[b], via B=At (NT).  M=512,K=1024.
__global__ __launch_bounds__(256) void gemm3_nt_out(const float* __restrict__ A,
                                                    const f16* __restrict__ Bt,
                                                    float* __restrict__ C) {
    const int K = 1024;
    const int b = blockIdx.z;
    A += (size_t)b * 512 * K;
    Bt += (size_t)b * 1024 * K;
    C += (size_t)b * 512 * 1024;
    __shared__ __attribute__((aligned(16))) f16 As[128 * 40];  // padded (manual staging)
    __shared__ __attribute__((aligned(16))) f16 Bs[128 * 32];
    const int tid = threadIdx.x, lane = tid & 63, wave = tid >> 6;
    const int m0 = blockIdx.y * 128, n0 = blockIdx.x * 128;
    const int col = lane & 15, quad = lane >> 4;
    const int wm = (wave & 1) * 64, wn = (wave >> 1) * 64;
    const int off0 = wave * 2048 + lane * 16, off1 = off0 + 1024;
    const char* gB0 = (const char*)(Bt + (size_t)(n0 + (off0 >> 6)) * K) + (off0 & 63);
    const char* gB1 = (const char*)(Bt + (size_t)(n0 + (off1 >> 6)) * K) + (off1 & 63);
    char* lB = (char*)Bs + wave * 2048;
    const int arow = tid >> 1, ahalf = (tid & 1) * 16;
    const float* gA = A + (size_t)(m0 + arow) * K + ahalf;

    f32x4 acc[4][4] = {};
    for (int k0 = 0; k0 < K; k0 += 32) {
        glds16(gB0 + k0 * 2, lB);
        glds16(gB1 + k0 * 2, lB + 1024);
        f32x4 x0 = *(const f32x4*)(gA + k0);
        f32x4 x1 = *(const f32x4*)(gA + k0 + 4);
        f32x4 x2 = *(const f32x4*)(gA + k0 + 8);
        f32x4 x3 = *(const f32x4*)(gA + k0 + 12);
        f16x8 h0, h1;
#pragma unroll
        for (int i = 0; i < 4; ++i) {
            h0[i] = (f16)x0[i]; h0[i + 4] = (f16)x1[i];
            h1[i] = (f16)x2[i]; h1[i + 4] = (f16)x3[i];
        }
        *(f16x8*)&As[arow * 40 + ahalf] = h0;
        *(f16x8*)&As[arow * 40 + ahalf + 8] = h1;
        __syncthreads();
        f16x8 fa[4], fb[4];
#pragma unroll
        for (int u = 0; u < 4; ++u) {
            fa[u] = *(const f16x8*)&As[(wm + u * 16 + col) * 40 + quad * 8];
            fb[u] = *(const f16x8*)&Bs[(wn + u * 16 + col) * 32 + quad * 8];
        }
#pragma unroll
        for (int u = 0; u < 4; ++u)
#pragma unroll
            for (int v = 0; v < 4; ++v)
                acc[u][v] = __builtin_amdgcn_mfma_f32_16x16x32_f16(fa[u], fb[v], acc[u][v], 0, 0, 0);
        __syncthreads();
    }
#pragma unroll
    for (int u = 0; u < 4; ++u)
#pragma unroll
        for (int v = 0; v < 4; ++v)
#pragma unroll
            for (int r = 0; r < 4; ++r)
                C[(size_t)(m0 + wm + u * 16 + quad * 4 + r) * 1024 + n0 + wn + v * 16 + col] =
                    acc[u][v][r];
}

// ---------------------------------------------------------------------------
// In-place row softmax on fp16 rows of length 1024. One block per row.
__global__ __launch_bounds__(256) void softmax_f16(f16* __restrict__ E) {
    f16x4* row = (f16x4*)(E + (size_t)blockIdx.x * 1024);
    const int tid = threadIdx.x;
    f16x4 v4 = row[tid];
    float v[4];
#pragma unroll
    for (int s = 0; s < 4; ++s) v[s] = (float)v4[s];
    float lmax = fmaxf(fmaxf(v[0], v[1]), fmaxf(v[2], v[3]));
#pragma unroll
    for (int off = 32; off; off >>= 1) lmax = fmaxf(lmax, __shfl_down(lmax, off, 64));
    __shared__ float sm[4], ss[4];
    const int wave = tid >> 6, lane = tid & 63;
    if (lane == 0) sm[wave] = lmax;
    __syncthreads();
    const float rmax = fmaxf(fmaxf(sm[0], sm[1]), fmaxf(sm[2], sm[3]));
    float lsum = 0.f;
#pragma unroll
    for (int s = 0; s < 4; ++s) {
        v[s] = __expf(v[s] - rmax);
        lsum += v[s];
    }
#pragma unroll
    for (int off = 32; off; off >>= 1) lsum += __shfl_down(lsum, off, 64);
    if (lane == 0) ss[wave] = lsum;
    __syncthreads();
    const float inv = 1.0f / (ss[0] + ss[1] + ss[2] + ss[3]);
    f16x4 o;
#pragma unroll
    for (int s = 0; s < 4; ++s) o[s] = (f16)(v[s] * inv);
    row[tid] = o;
}

// ---------------------------------------------------------------------------
extern "C" void kernel_launch(void* const* d_in, const int* in_sizes, int n_in,
                              void* d_out, int out_size, void* d_ws, size_t ws_size,
                              hipStream_t stream) {
    const float* n1 = (const float*)d_in[0];
    const float* n2 = (const float*)d_in[1];
    const float* Wc = (const float*)d_in[2];
    float* out = (float*)d_out;
    char* ws = (char*)d_ws;

    f16* n2t = (f16*)(ws);                       // 16 MiB
    f16* Xt  = (f16*)(ws + (16u << 20));         // 16 MiB
    f16* E   = (f16*)(ws + (32u << 20));         // 32 MiB (softmax in-place)
    f16* n1f = (f16*)(ws + (64u << 20));         // 16 MiB
    f16* Wf  = (f16*)(ws + (80u << 20));         // 2 MiB
    f16* At  = (f16*)(ws + (64u << 20));         // 32 MiB (aliases n1f+Wf)

    dim3 blk(256);
    cvt_f32_f16<<<4096, blk, 0, stream>>>(n1, n1f);                 // 16*512*1024 / 8
    cvt_f32_f16<<<512, blk, 0, stream>>>(Wc, Wf);                   // 1024*1024 / 8
    tr_f32_f16<<<dim3(16, 8, 16), blk, 0, stream>>>(n2, n2t);
    gemm1_nt_xt<<<dim3(8, 4, 16), blk, 0, stream>>>(n1f, Wf, Xt);
    gemm2_nt_e<<<dim3(8, 8, 16), blk, 0, stream>>>(Xt, n2t, E);
    softmax_f16<<<16384, blk, 0, stream>>>(E);
    tr_f16<<<dim3(16, 16, 16), blk, 0, stream>>>(E, At);
    gemm3_nt_out<<<dim3(8, 4, 16), blk, 0, stream>>>(n2, At, out);
}

// Round 4
// 236.509 us; speedup vs baseline: 4.2143x; 1.0695x over previous
//
#include <hip/hip_runtime.h>
#include <math.h>

// B=16, C=512, HW=1024.  Chain (per batch):
//   X  (C x HW)  = n1 @ W_c^T
//   E  (HW x HW) = X^T @ n2
//   A  = row-softmax(E)
//   out(C x HW)  = n2 @ A
//
// Round 4: all-fp16 MFMA pipeline; every GEMM is the m97 NT structure
// (128x128 tile, BK=32, global_load_lds width=16, zero staging VALU).
// New this round: gemm3 consumes pre-converted n2f (f16) instead of fp32
// n2 (round-3 gemm3 re-fetched 147 MB + burned VALU on cvt); the three
// pre-pass kernels are fused into one `prep` launch (8 -> 6 dispatches).
//
// Workspace (96 MiB budget, lifetime-aliased):
//   [0,16M):   n2t  f16 [b][h][c]  (prep -> gemm2)   } At [0,32M) after gemm2
//   [16,32M):  Xt   f16 [b][o][c]  (gemm1 -> gemm2)  }
//   [32,34M):  Wf   f16            (prep -> gemm1; overlays E, written later)
//   [32,64M):  E    f16 [b][o][h]  (gemm2 -> tr_f16; softmax in-place)
//   [64,80M):  n1f  f16            (prep -> gemm1)
//   [80,96M):  n2f  f16 [b][c][h]  (prep -> gemm3)

typedef _Float16 f16;
typedef _Float16 f16x8 __attribute__((ext_vector_type(8)));
typedef _Float16 f16x4 __attribute__((ext_vector_type(4)));
typedef float f32x4 __attribute__((ext_vector_type(4)));

__device__ __forceinline__ void glds16(const void* g, void* l) {
    __builtin_amdgcn_global_load_lds((const __attribute__((address_space(1))) void*)g,
                                     (__attribute__((address_space(3))) void*)l, 16, 0, 0);
}

// ---------------------------------------------------------------------------
// Fused pre-pass. blockIdx.x ranges:
//   [0,4096):    n1  f32 -> n1f f16            (8 elems/thread)
//   [4096,4608): Wc  f32 -> Wf  f16
//   [4608,6656): n2  f32 -> n2f f16 (natural) + n2t f16 (transposed)
__global__ __launch_bounds__(256) void prep(const float* __restrict__ n1,
                                            const float* __restrict__ Wc,
                                            const float* __restrict__ n2,
                                            f16* __restrict__ n1f, f16* __restrict__ Wf,
                                            f16* __restrict__ n2f, f16* __restrict__ n2t) {
    const int bid = blockIdx.x, tid = threadIdx.x;
    if (bid < 4608) {
        const float* s = (bid < 4096) ? n1 : Wc;
        f16* d = (bid < 4096) ? n1f : Wf;
        const size_t i = ((size_t)(bid < 4096 ? bid : bid - 4096) * 256 + tid) * 8;
        f32x4 a = *(const f32x4*)(s + i);
        f32x4 b = *(const f32x4*)(s + i + 4);
        f16x8 o;
        o[0] = (f16)a[0]; o[1] = (f16)a[1]; o[2] = (f16)a[2]; o[3] = (f16)a[3];
        o[4] = (f16)b[0]; o[5] = (f16)b[1]; o[6] = (f16)b[2]; o[7] = (f16)b[3];
        *(f16x8*)(d + i) = o;
        return;
    }
    // n2 dual-write: 64x64 f32 tiles. id -> (b, row-strip ry of 512, col-strip cx of 1024)
    const int id = bid - 4608;          // 0..2047
    const int b = id >> 7;              // 16 batches
    const int ry = (id & 127) >> 4;     // 8 strips over 512 rows
    const int cx = id & 15;             // 16 strips over 1024 cols
    const float* S = n2 + (size_t)b * 512 * 1024;
    f16* Dn = n2f + (size_t)b * 512 * 1024;
    f16* Dt = n2t + (size_t)b * 1024 * 512;
    __shared__ f16 Ts[64 * 72];
    const int r0 = ry * 64, c0 = cx * 64;
    const int rr = tid >> 3, cc8 = (tid & 7) * 8;
#pragma unroll
    for (int h = 0; h < 2; ++h) {
        const int row = r0 + rr + 32 * h;
        const float* s = S + (size_t)row * 1024 + c0 + cc8;
        f32x4 a = *(const f32x4*)s, bq = *(const f32x4*)(s + 4);
        f16x8 o;
        o[0] = (f16)a[0]; o[1] = (f16)a[1]; o[2] = (f16)a[2]; o[3] = (f16)a[3];
        o[4] = (f16)bq[0]; o[5] = (f16)bq[1]; o[6] = (f16)bq[2]; o[7] = (f16)bq[3];
        *(f16x8*)&Ts[(rr + 32 * h) * 72 + cc8] = o;
        *(f16x8*)(Dn + (size_t)row * 1024 + c0 + cc8) = o;  // natural f16 copy
    }
    __syncthreads();
    const int j = tid >> 2, k16 = (tid & 3) * 16;
    f16* d = Dt + (size_t)(c0 + j) * 512 + r0 + k16;
    f16x8 o0, o1;
#pragma unroll
    for (int i = 0; i < 8; ++i) {
        o0[i] = Ts[(k16 + i) * 72 + j];
        o1[i] = Ts[(k16 + 8 + i) * 72 + j];
    }
    *(f16x8*)d = o0;
    *(f16x8*)(d + 8) = o1;
}

// ---------------------------------------------------------------------------
// A [b][1024][1024] f16 -> At [b][1024][1024] f16 transposed
__global__ __launch_bounds__(256) void tr_f16(const f16* __restrict__ S,
                                              f16* __restrict__ D) {
    const int b = blockIdx.z;
    S += (size_t)b * 1024 * 1024;
    D += (size_t)b * 1024 * 1024;
    __shared__ f16 Ts[64 * 72];
    const int r0 = blockIdx.y * 64, c0 = blockIdx.x * 64;
    const int tid = threadIdx.x;
    const int rr = tid >> 3, cc8 = (tid & 7) * 8;
#pragma unroll
    for (int h = 0; h < 2; ++h)
        *(f16x8*)&Ts[(rr + 32 * h) * 72 + cc8] =
            *(const f16x8*)(S + (size_t)(r0 + rr + 32 * h) * 1024 + c0 + cc8);
    __syncthreads();
    const int j = tid >> 2, k16 = (tid & 3) * 16;
    f16* d = D + (size_t)(c0 + j) * 1024 + r0 + k16;
    f16x8 o0, o1;
#pragma unroll
    for (int i = 0; i < 8; ++i) {
        o0[i] = Ts[(k16 + i) * 72 + j];
        o1[i] = Ts[(k16 + 8 + i) * 72 + j];
    }
    *(f16x8*)d = o0;
    *(f16x8*)(d + 8) = o1;
}

// ---------------------------------------------------------------------------
// GEMM1: Xt[b][o][c] = (n1f[b] @ Wf^T)^T.  A=n1f (M=512,K=1024), B=Wf (N=1024).
__global__ __launch_bounds__(256) void gemm1_nt_xt(const f16* __restrict__ A,
                                                   const f16* __restrict__ Bw,
                                                   f16* __restrict__ Xt) {
    const int M = 512, K = 1024;
    const int b = blockIdx.z;
    A += (size_t)b * M * K;
    Xt += (size_t)b * 1024 * M;
    __shared__ __attribute__((aligned(16))) f16 As[128 * 32], Bs[128 * 32];
    __shared__ __attribute__((aligned(16))) f16 Tt[128 * 136];
    const int tid = threadIdx.x, lane = tid & 63, wave = tid >> 6;
    const int m0 = blockIdx.y * 128, n0 = blockIdx.x * 128;
    const int col = lane & 15, quad = lane >> 4;
    const int wm = (wave & 1) * 64, wn = (wave >> 1) * 64;
    const int off0 = wave * 2048 + lane * 16, off1 = off0 + 1024;
    const char* gA0 = (const char*)(A + (size_t)(m0 + (off0 >> 6)) * K) + (off0 & 63);
    const char* gA1 = (const char*)(A + (size_t)(m0 + (off1 >> 6)) * K) + (off1 & 63);
    const char* gB0 = (const char*)(Bw + (size_t)(n0 + (off0 >> 6)) * K) + (off0 & 63);
    const char* gB1 = (const char*)(Bw + (size_t)(n0 + (off1 >> 6)) * K) + (off1 & 63);
    char* lA = (char*)As + wave * 2048;
    char* lB = (char*)Bs + wave * 2048;

    f32x4 acc[4][4] = {};
    for (int kb = 0; kb < K * 2; kb += 64) {
        glds16(gA0 + kb, lA);
        glds16(gA1 + kb, lA + 1024);
        glds16(gB0 + kb, lB);
        glds16(gB1 + kb, lB + 1024);
        __syncthreads();
        f16x8 fa[4], fb[4];
#pragma unroll
        for (int u = 0; u < 4; ++u) {
            fa[u] = *(const f16x8*)&As[(wm + u * 16 + col) * 32 + quad * 8];
            fb[u] = *(const f16x8*)&Bs[(wn + u * 16 + col) * 32 + quad * 8];
        }
#pragma unroll
        for (int u = 0; u < 4; ++u)
#pragma unroll
            for (int v = 0; v < 4; ++v)
                acc[u][v] = __builtin_amdgcn_mfma_f32_16x16x32_f16(fa[u], fb[v], acc[u][v], 0, 0, 0);
        __syncthreads();
    }
    // Transposed epilogue: Tt[n][m] (pad 136), then coalesced rows of Xt.
#pragma unroll
    for (int u = 0; u < 4; ++u)
#pragma unroll
        for (int v = 0; v < 4; ++v) {
            f16x4 p;
#pragma unroll
            for (int r = 0; r < 4; ++r) p[r] = (f16)acc[u][v][r];
            *(f16x4*)&Tt[(wn + v * 16 + col) * 136 + wm + u * 16 + quad * 4] = p;
        }
    __syncthreads();
    const int j = tid >> 1, half = (tid & 1) * 64;
    f16* dst = Xt + (size_t)(n0 + j) * M + m0 + half;
#pragma unroll
    for (int c8 = 0; c8 < 64; c8 += 8)
        *(f16x8*)(dst + c8) = *(const f16x8*)&Tt[j * 136 + half + c8];
}

// ---------------------------------------------------------------------------
// GEMM2: E[b][o][h] (f16) = Xt[b] @ n2t[b]^T.  M=N=1024, K=512.
__global__ __launch_bounds__(256) void gemm2_nt_e(const f16* __restrict__ A,
                                                  const f16* __restrict__ B,
                                                  f16* __restrict__ E) {
    const int K = 512;
    const int b = blockIdx.z;
    A += (size_t)b * 1024 * K;
    B += (size_t)b * 1024 * K;
    E += (size_t)b * 1024 * 1024;
    __shared__ __attribute__((aligned(16))) f16 As[128 * 32], Bs[128 * 32];
    const int tid = threadIdx.x, lane = tid & 63, wave = tid >> 6;
    const int m0 = blockIdx.y * 128, n0 = blockIdx.x * 128;
    const int col = lane & 15, quad = lane >> 4;
    const int wm = (wave & 1) * 64, wn = (wave >> 1) * 64;
    const int off0 = wave * 2048 + lane * 16, off1 = off0 + 1024;
    const char* gA0 = (const char*)(A + (size_t)(m0 + (off0 >> 6)) * K) + (off0 & 63);
    const char* gA1 = (const char*)(A + (size_t)(m0 + (off1 >> 6)) * K) + (off1 & 63);
    const char* gB0 = (const char*)(B + (size_t)(n0 + (off0 >> 6)) * K) + (off0 & 63);
    const char* gB1 = (const char*)(B + (size_t)(n0 + (off1 >> 6)) * K) + (off1 & 63);
    char* lA = (char*)As + wave * 2048;
    char* lB = (char*)Bs + wave * 2048;

    f32x4 acc[4][4] = {};
    for (int kb = 0; kb < K * 2; kb += 64) {
        glds16(gA0 + kb, lA);
        glds16(gA1 + kb, lA + 1024);
        glds16(gB0 + kb, lB);
        glds16(gB1 + kb, lB + 1024);
        __syncthreads();
        f16x8 fa[4], fb[4];
#pragma unroll
        for (int u = 0; u < 4; ++u) {
            fa[u] = *(const f16x8*)&As[(wm + u * 16 + col) * 32 + quad * 8];
            fb[u] = *(const f16x8*)&Bs[(wn + u * 16 + col) * 32 + quad * 8];
        }
#pragma unroll
        for (int u = 0; u < 4; ++u)
#pragma unroll
            for (int v = 0; v < 4; ++v)
                acc[u][v] = __builtin_amdgcn_mfma_f32_16x16x32_f16(fa[u], fb[v], acc[u][v], 0, 0, 0);
        __syncthreads();
    }
#pragma unroll
    for (int u = 0; u < 4; ++u)
#pragma unroll
        for (int v = 0; v < 4; ++v)
#pragma unroll
            for (int r = 0; r < 4; ++r)
                E[(size_t)(m0 + wm + u * 16 + quad * 4 + r) * 1024 + n0 + wn + v * 16 + col] =
                    (f16)acc[u][v][r];
}

// ---------------------------------------------------------------------------
// GEMM3: out[b][c][j] (f32) = n2f[b](f16) @ At[b]^T.  M=512, N=1024, K=1024.
// Same K-loop as gemm2; fp32 epilogue.
__global__ __launch_bounds__(256) void gemm3_nt_out(const f16* __restrict__ A,
                                                    const f16* __restrict__ Bt,
                                                    float* __restrict__ C) {
    const int K = 1024;
    const int b = blockIdx.z;
    A += (size_t)b * 512 * K;
    Bt += (size_t)b * 1024 * K;
    C += (size_t)b * 512 * 1024;
    __shared__ __attribute__((aligned(16))) f16 As[128 * 32], Bs[128 * 32];
    const int tid = threadIdx.x, lane = tid & 63, wave = tid >> 6;
    const int m0 = blockIdx.y * 128, n0 = blockIdx.x * 128;
    const int col = lane & 15, quad = lane >> 4;
    const int wm = (wave & 1) * 64, wn = (wave >> 1) * 64;
    const int off0 = wave * 2048 + lane * 16, off1 = off0 + 1024;
    const char* gA0 = (const char*)(A + (size_t)(m0 + (off0 >> 6)) * K) + (off0 & 63);
    const char* gA1 = (const char*)(A + (size_t)(m0 + (off1 >> 6)) * K) + (off1 & 63);
    const char* gB0 = (const char*)(Bt + (size_t)(n0 + (off0 >> 6)) * K) + (off0 & 63);
    const char* gB1 = (const char*)(Bt + (size_t)(n0 + (off1 >> 6)) * K) + (off1 & 63);
    char* lA = (char*)As + wave * 2048;
    char* lB = (char*)Bs + wave * 2048;

    f32x4 acc[4][4] = {};
    for (int kb = 0; kb < K * 2; kb += 64) {
        glds16(gA0 + kb, lA);
        glds16(gA1 + kb, lA + 1024);
        glds16(gB0 + kb, lB);
        glds16(gB1 + kb, lB + 1024);
        __syncthreads();
        f16x8 fa[4], fb[4];
#pragma unroll
        for (int u = 0; u < 4; ++u) {
            fa[u] = *(const f16x8*)&As[(wm + u * 16 + col) * 32 + quad * 8];
            fb[u] = *(const f16x8*)&Bs[(wn + u * 16 + col) * 32 + quad * 8];
        }
#pragma unroll
        for (int u = 0; u < 4; ++u)
#pragma unroll
            for (int v = 0; v < 4; ++v)
                acc[u][v] = __builtin_amdgcn_mfma_f32_16x16x32_f16(fa[u], fb[v], acc[u][v], 0, 0, 0);
        __syncthreads();
    }
#pragma unroll
    for (int u = 0; u < 4; ++u)
#pragma unroll
        for (int v = 0; v < 2; ++v)
#pragma unroll
            for (int r = 0; r < 4; ++r) {
                C[(size_t)(m0 + wm + u * 16 + quad * 4 + r) * 1024 + n0 + wn + v * 16 + col] =
                    acc[u][v][r];
                C[(size_t)(m0 + wm + u * 16 + quad * 4 + r) * 1024 + n0 + wn + (v + 2) * 16 + col] =
                    acc[u][v + 2][r];
            }
}

// ---------------------------------------------------------------------------
// In-place row softmax on fp16 rows of length 1024. One block per row.
__global__ __launch_bounds__(256) void softmax_f16(f16* __restrict__ E) {
    f16x4* row = (f16x4*)(E + (size_t)blockIdx.x * 1024);
    const int tid = threadIdx.x;
    f16x4 v4 = row[tid];
    float v[4];
#pragma unroll
    for (int s = 0; s < 4; ++s) v[s] = (float)v4[s];
    float lmax = fmaxf(fmaxf(v[0], v[1]), fmaxf(v[2], v[3]));
#pragma unroll
    for (int off = 32; off; off >>= 1) lmax = fmaxf(lmax, __shfl_down(lmax, off, 64));
    __shared__ float sm[4], ss[4];
    const int wave = tid >> 6, lane = tid & 63;
    if (lane == 0) sm[wave] = lmax;
    __syncthreads();
    const float rmax = fmaxf(fmaxf(sm[0], sm[1]), fmaxf(sm[2], sm[3]));
    float lsum = 0.f;
#pragma unroll
    for (int s = 0; s < 4; ++s) {
        v[s] = __expf(v[s] - rmax);
        lsum += v[s];
    }
#pragma unroll
    for (int off = 32; off; off >>= 1) lsum += __shfl_down(lsum, off, 64);
    if (lane == 0) ss[wave] = lsum;
    __syncthreads();
    const float inv = 1.0f / (ss[0] + ss[1] + ss[2] + ss[3]);
    f16x4 o;
#pragma unroll
    for (int s = 0; s < 4; ++s) o[s] = (f16)(v[s] * inv);
    row[tid] = o;
}

// ---------------------------------------------------------------------------
extern "C" void kernel_launch(void* const* d_in, const int* in_sizes, int n_in,
                              void* d_out, int out_size, void* d_ws, size_t ws_size,
                              hipStream_t stream) {
    const float* n1 = (const float*)d_in[0];
    const float* n2 = (const float*)d_in[1];
    const float* Wc = (const float*)d_in[2];
    float* out = (float*)d_out;
    char* ws = (char*)d_ws;

    f16* n2t = (f16*)(ws);                  // [0,16M)   prep -> gemm2
    f16* Xt  = (f16*)(ws + (16u << 20));    // [16,32M)  gemm1 -> gemm2
    f16* Wf  = (f16*)(ws + (32u << 20));    // [32,34M)  prep -> gemm1 (dead before E written)
    f16* E   = (f16*)(ws + (32u << 20));    // [32,64M)  gemm2 -> tr_f16 (softmax in place)
    f16* n1f = (f16*)(ws + (64u << 20));    // [64,80M)  prep -> gemm1
    f16* n2f = (f16*)(ws + (80u << 20));    // [80,96M)  prep -> gemm3
    f16* At  = (f16*)(ws);                  // [0,32M)   tr_f16 -> gemm3 (over dead n2t+Xt)

    dim3 blk(256);
    prep<<<6656, blk, 0, stream>>>(n1, Wc, n2, n1f, Wf, n2f, n2t);
    gemm1_nt_xt<<<dim3(8, 4, 16), blk, 0, stream>>>(n1f, Wf, Xt);
    gemm2_nt_e<<<dim3(8, 8, 16), blk, 0, stream>>>(Xt, n2t, E);
    softmax_f16<<<16384, blk, 0, stream>>>(E);
    tr_f16<<<dim3(16, 16, 16), blk, 0, stream>>>(E, At);
    gemm3_nt_out<<<dim3(8, 4, 16), blk, 0, stream>>>(n2f, At, out);
}

// Round 5
// 217.577 us; speedup vs baseline: 4.5811x; 1.0870x over previous
//
#include <hip/hip_runtime.h>
#include <math.h>

// B=16, C=512, HW=1024.  Chain (per batch):
//   X  (C x HW)  = n1 @ W_c^T
//   E  (HW x HW) = X^T @ n2
//   A  = row-softmax(E)
//   out(C x HW)  = n2 @ A
//
// Round 5: all-fp16 MFMA (m97 NT structure: 128x128 tile, BK=32,
// global_load_lds width=16). New:
//  - XCD-aware swizzled 1D grids on all GEMMs: 2 batches per XCD so each
//    batch's A+B (<=3 MiB) is L2-resident once (round-3 gemm3 FETCH was
//    147 MB vs 48 ideal from cross-XCD B re-fetch).
//  - softmax pass now computes row stats only (m, 1/s); the transpose pass
//    applies exp(x-m)/s during load. Saves a full 32 MB E rewrite.
//
// Workspace (96 MiB + nothing new; lifetime-aliased):
//   [0,16M):   n2t  f16 (prep -> gemm2)      } At [0,32M) after gemm2
//   [16,32M):  Xt   f16 (gemm1 -> gemm2)     }
//   [32,34M):  Wf   f16 (prep -> gemm1; overlays E, written later)
//   [32,64M):  E    f16 (gemm2 -> tr_scale)
//   [64,80M):  n1f  f16 (prep -> gemm1); stats Mg/Si overlay it afterwards
//   [80,96M):  n2f  f16 (prep -> gemm3)

typedef _Float16 f16;
typedef _Float16 f16x8 __attribute__((ext_vector_type(8)));
typedef _Float16 f16x4 __attribute__((ext_vector_type(4)));
typedef float f32x4 __attribute__((ext_vector_type(4)));

__device__ __forceinline__ void glds16(const void* g, void* l) {
    __builtin_amdgcn_global_load_lds((const __attribute__((address_space(1))) void*)g,
                                     (__attribute__((address_space(3))) void*)l, 16, 0, 0);
}

// ---------------------------------------------------------------------------
// Fused pre-pass. blockIdx.x ranges:
//   [0,4096):    n1  f32 -> n1f f16
//   [4096,4608): Wc  f32 -> Wf  f16
//   [4608,6656): n2  f32 -> n2f f16 (natural) + n2t f16 (transposed)
__global__ __launch_bounds__(256) void prep(const float* __restrict__ n1,
                                            const float* __restrict__ Wc,
                                            const float* __restrict__ n2,
                                            f16* __restrict__ n1f, f16* __restrict__ Wf,
                                            f16* __restrict__ n2f, f16* __restrict__ n2t) {
    const int bid = blockIdx.x, tid = threadIdx.x;
    if (bid < 4608) {
        const float* s = (bid < 4096) ? n1 : Wc;
        f16* d = (bid < 4096) ? n1f : Wf;
        const size_t i = ((size_t)(bid < 4096 ? bid : bid - 4096) * 256 + tid) * 8;
        f32x4 a = *(const f32x4*)(s + i);
        f32x4 b = *(const f32x4*)(s + i + 4);
        f16x8 o;
        o[0] = (f16)a[0]; o[1] = (f16)a[1]; o[2] = (f16)a[2]; o[3] = (f16)a[3];
        o[4] = (f16)b[0]; o[5] = (f16)b[1]; o[6] = (f16)b[2]; o[7] = (f16)b[3];
        *(f16x8*)(d + i) = o;
        return;
    }
    const int id = bid - 4608;          // 0..2047
    const int b = id >> 7;
    const int ry = (id & 127) >> 4;
    const int cx = id & 15;
    const float* S = n2 + (size_t)b * 512 * 1024;
    f16* Dn = n2f + (size_t)b * 512 * 1024;
    f16* Dt = n2t + (size_t)b * 1024 * 512;
    __shared__ f16 Ts[64 * 72];
    const int r0 = ry * 64, c0 = cx * 64;
    const int rr = tid >> 3, cc8 = (tid & 7) * 8;
#pragma unroll
    for (int h = 0; h < 2; ++h) {
        const int row = r0 + rr + 32 * h;
        const float* s = S + (size_t)row * 1024 + c0 + cc8;
        f32x4 a = *(const f32x4*)s, bq = *(const f32x4*)(s + 4);
        f16x8 o;
        o[0] = (f16)a[0]; o[1] = (f16)a[1]; o[2] = (f16)a[2]; o[3] = (f16)a[3];
        o[4] = (f16)bq[0]; o[5] = (f16)bq[1]; o[6] = (f16)bq[2]; o[7] = (f16)bq[3];
        *(f16x8*)&Ts[(rr + 32 * h) * 72 + cc8] = o;
        *(f16x8*)(Dn + (size_t)row * 1024 + c0 + cc8) = o;
    }
    __syncthreads();
    const int j = tid >> 2, k16 = (tid & 3) * 16;
    f16* d = Dt + (size_t)(c0 + j) * 512 + r0 + k16;
    f16x8 o0, o1;
#pragma unroll
    for (int i = 0; i < 8; ++i) {
        o0[i] = Ts[(k16 + i) * 72 + j];
        o1[i] = Ts[(k16 + 8 + i) * 72 + j];
    }
    *(f16x8*)d = o0;
    *(f16x8*)(d + 8) = o1;
}

// ---------------------------------------------------------------------------
// Row stats: per E-row max m and inv-sum 1/s of exp(x-m). One wave per row.
__global__ __launch_bounds__(256) void softmax_stats(const f16* __restrict__ E,
                                                     float* __restrict__ Mg,
                                                     float* __restrict__ Si) {
    const int wave = threadIdx.x >> 6, lane = threadIdx.x & 63;
    const int row = blockIdx.x * 4 + wave;
    const f16* p = E + (size_t)row * 1024 + lane * 16;
    f16x8 a = *(const f16x8*)p, b = *(const f16x8*)(p + 8);
    float v[16];
#pragma unroll
    for (int i = 0; i < 8; ++i) { v[i] = (float)a[i]; v[i + 8] = (float)b[i]; }
    float m = v[0];
#pragma unroll
    for (int i = 1; i < 16; ++i) m = fmaxf(m, v[i]);
#pragma unroll
    for (int off = 1; off < 64; off <<= 1) m = fmaxf(m, __shfl_xor(m, off, 64));
    float s = 0.f;
#pragma unroll
    for (int i = 0; i < 16; ++i) s += __expf(v[i] - m);
#pragma unroll
    for (int off = 1; off < 64; off <<= 1) s += __shfl_xor(s, off, 64);
    if (lane == 0) { Mg[row] = m; Si[row] = 1.0f / s; }
}

// ---------------------------------------------------------------------------
// At[b][j][k] = exp(E[b][k][j] - m_k) / s_k   (scaled transpose, 64x64 tiles)
__global__ __launch_bounds__(256) void tr_scale(const f16* __restrict__ S,
                                                const float* __restrict__ Mg,
                                                const float* __restrict__ Si,
                                                f16* __restrict__ D) {
    const int b = blockIdx.z;
    S += (size_t)b * 1024 * 1024;
    D += (size_t)b * 1024 * 1024;
    __shared__ f16 Ts[64 * 72];
    const int r0 = blockIdx.y * 64, c0 = blockIdx.x * 64;
    const int tid = threadIdx.x;
    const int rr = tid >> 3, cc8 = (tid & 7) * 8;
#pragma unroll
    for (int h = 0; h < 2; ++h) {
        const int row = r0 + rr + 32 * h;
        const float mg = Mg[b * 1024 + row];
        const float si = Si[b * 1024 + row];
        f16x8 v = *(const f16x8*)(S + (size_t)row * 1024 + c0 + cc8);
        f16x8 o;
#pragma unroll
        for (int i = 0; i < 8; ++i) o[i] = (f16)(__expf((float)v[i] - mg) * si);
        *(f16x8*)&Ts[(rr + 32 * h) * 72 + cc8] = o;
    }
    __syncthreads();
    const int j = tid >> 2, k16 = (tid & 3) * 16;
    f16* d = D + (size_t)(c0 + j) * 1024 + r0 + k16;
    f16x8 o0, o1;
#pragma unroll
    for (int i = 0; i < 8; ++i) {
        o0[i] = Ts[(k16 + i) * 72 + j];
        o1[i] = Ts[(k16 + 8 + i) * 72 + j];
    }
    *(f16x8*)d = o0;
    *(f16x8*)(d + 8) = o1;
}

// ---------------------------------------------------------------------------
// GEMM1: Xt[b][o][c] = (n1f[b] @ Wf^T)^T.  M=512, N=1024, K=1024.
// 1D swizzled grid (512): 2 batches per XCD.
__global__ __launch_bounds__(256) void gemm1_nt_xt(const f16* __restrict__ A,
                                                   const f16* __restrict__ Bw,
                                                   f16* __restrict__ Xt) {
    const int M = 512, K = 1024;
    const int id = blockIdx.x;
    const int xcd = id & 7, loc = id >> 3;
    const int b = xcd * 2 + (loc >> 5);
    const int m0 = ((loc >> 3) & 3) * 128;
    const int n0 = (loc & 7) * 128;
    A += (size_t)b * M * K;
    Xt += (size_t)b * 1024 * M;
    __shared__ __attribute__((aligned(16))) f16 As[128 * 32], Bs[128 * 32];
    __shared__ __attribute__((aligned(16))) f16 Tt[128 * 136];
    const int tid = threadIdx.x, lane = tid & 63, wave = tid >> 6;
    const int col = lane & 15, quad = lane >> 4;
    const int wm = (wave & 1) * 64, wn = (wave >> 1) * 64;
    const int off0 = wave * 2048 + lane * 16, off1 = off0 + 1024;
    const char* gA0 = (const char*)(A + (size_t)(m0 + (off0 >> 6)) * K) + (off0 & 63);
    const char* gA1 = (const char*)(A + (size_t)(m0 + (off1 >> 6)) * K) + (off1 & 63);
    const char* gB0 = (const char*)(Bw + (size_t)(n0 + (off0 >> 6)) * K) + (off0 & 63);
    const char* gB1 = (const char*)(Bw + (size_t)(n0 + (off1 >> 6)) * K) + (off1 & 63);
    char* lA = (char*)As + wave * 2048;
    char* lB = (char*)Bs + wave * 2048;

    f32x4 acc[4][4] = {};
    for (int kb = 0; kb < K * 2; kb += 64) {
        glds16(gA0 + kb, lA);
        glds16(gA1 + kb, lA + 1024);
        glds16(gB0 + kb, lB);
        glds16(gB1 + kb, lB + 1024);
        __syncthreads();
        f16x8 fa[4], fb[4];
#pragma unroll
        for (int u = 0; u < 4; ++u) {
            fa[u] = *(const f16x8*)&As[(wm + u * 16 + col) * 32 + quad * 8];
            fb[u] = *(const f16x8*)&Bs[(wn + u * 16 + col) * 32 + quad * 8];
        }
#pragma unroll
        for (int u = 0; u < 4; ++u)
#pragma unroll
            for (int v = 0; v < 4; ++v)
                acc[u][v] = __builtin_amdgcn_mfma_f32_16x16x32_f16(fa[u], fb[v], acc[u][v], 0, 0, 0);
        __syncthreads();
    }
#pragma unroll
    for (int u = 0; u < 4; ++u)
#pragma unroll
        for (int v = 0; v < 4; ++v) {
            f16x4 p;
#pragma unroll
            for (int r = 0; r < 4; ++r) p[r] = (f16)acc[u][v][r];
            *(f16x4*)&Tt[(wn + v * 16 + col) * 136 + wm + u * 16 + quad * 4] = p;
        }
    __syncthreads();
    const int j = tid >> 1, half = (tid & 1) * 64;
    f16* dst = Xt + (size_t)(n0 + j) * M + m0 + half;
#pragma unroll
    for (int c8 = 0; c8 < 64; c8 += 8)
        *(f16x8*)(dst + c8) = *(const f16x8*)&Tt[j * 136 + half + c8];
}

// ---------------------------------------------------------------------------
// GEMM2: E[b][o][h] (f16) = Xt[b] @ n2t[b]^T.  M=N=1024, K=512.
// 1D swizzled grid (1024): 2 batches per XCD.
__global__ __launch_bounds__(256) void gemm2_nt_e(const f16* __restrict__ A,
                                                  const f16* __restrict__ B,
                                                  f16* __restrict__ E) {
    const int K = 512;
    const int id = blockIdx.x;
    const int xcd = id & 7, loc = id >> 3;
    const int b = xcd * 2 + (loc >> 6);
    const int m0 = ((loc >> 3) & 7) * 128;
    const int n0 = (loc & 7) * 128;
    A += (size_t)b * 1024 * K;
    B += (size_t)b * 1024 * K;
    E += (size_t)b * 1024 * 1024;
    __shared__ __attribute__((aligned(16))) f16 As[128 * 32], Bs[128 * 32];
    const int tid = threadIdx.x, lane = tid & 63, wave = tid >> 6;
    const int col = lane & 15, quad = lane >> 4;
    const int wm = (wave & 1) * 64, wn = (wave >> 1) * 64;
    const int off0 = wave * 2048 + lane * 16, off1 = off0 + 1024;
    const char* gA0 = (const char*)(A + (size_t)(m0 + (off0 >> 6)) * K) + (off0 & 63);
    const char* gA1 = (const char*)(A + (size_t)(m0 + (off1 >> 6)) * K) + (off1 & 63);
    const char* gB0 = (const char*)(B + (size_t)(n0 + (off0 >> 6)) * K) + (off0 & 63);
    const char* gB1 = (const char*)(B + (size_t)(n0 + (off1 >> 6)) * K) + (off1 & 63);
    char* lA = (char*)As + wave * 2048;
    char* lB = (char*)Bs + wave * 2048;

    f32x4 acc[4][4] = {};
    for (int kb = 0; kb < K * 2; kb += 64) {
        glds16(gA0 + kb, lA);
        glds16(gA1 + kb, lA + 1024);
        glds16(gB0 + kb, lB);
        glds16(gB1 + kb, lB + 1024);
        __syncthreads();
        f16x8 fa[4], fb[4];
#pragma unroll
        for (int u = 0; u < 4; ++u) {
            fa[u] = *(const f16x8*)&As[(wm + u * 16 + col) * 32 + quad * 8];
            fb[u] = *(const f16x8*)&Bs[(wn + u * 16 + col) * 32 + quad * 8];
        }
#pragma unroll
        for (int u = 0; u < 4; ++u)
#pragma unroll
            for (int v = 0; v < 4; ++v)
                acc[u][v] = __builtin_amdgcn_mfma_f32_16x16x32_f16(fa[u], fb[v], acc[u][v], 0, 0, 0);
        __syncthreads();
    }
#pragma unroll
    for (int u = 0; u < 4; ++u)
#pragma unroll
        for (int v = 0; v < 4; ++v)
#pragma unroll
            for (int r = 0; r < 4; ++r)
                E[(size_t)(m0 + wm + u * 16 + quad * 4 + r) * 1024 + n0 + wn + v * 16 + col] =
                    (f16)acc[u][v][r];
}

// ---------------------------------------------------------------------------
// GEMM3: out[b][c][j] (f32) = n2f[b](f16) @ At[b]^T.  M=512, N=1024, K=1024.
// 1D swizzled grid (512): 2 batches per XCD.
__global__ __launch_bounds__(256) void gemm3_nt_out(const f16* __restrict__ A,
                                                    const f16* __restrict__ Bt,
                                                    float* __restrict__ C) {
    const int K = 1024;
    const int id = blockIdx.x;
    const int xcd = id & 7, loc = id >> 3;
    const int b = xcd * 2 + (loc >> 5);
    const int m0 = ((loc >> 3) & 3) * 128;
    const int n0 = (loc & 7) * 128;
    A += (size_t)b * 512 * K;
    Bt += (size_t)b * 1024 * K;
    C += (size_t)b * 512 * 1024;
    __shared__ __attribute__((aligned(16))) f16 As[128 * 32], Bs[128 * 32];
    const int tid = threadIdx.x, lane = tid & 63, wave = tid >> 6;
    const int col = lane & 15, quad = lane >> 4;
    const int wm = (wave & 1) * 64, wn = (wave >> 1) * 64;
    const int off0 = wave * 2048 + lane * 16, off1 = off0 + 1024;
    const char* gA0 = (const char*)(A + (size_t)(m0 + (off0 >> 6)) * K) + (off0 & 63);
    const char* gA1 = (const char*)(A + (size_t)(m0 + (off1 >> 6)) * K) + (off1 & 63);
    const char* gB0 = (const char*)(Bt + (size_t)(n0 + (off0 >> 6)) * K) + (off0 & 63);
    const char* gB1 = (const char*)(Bt + (size_t)(n0 + (off1 >> 6)) * K) + (off1 & 63);
    char* lA = (char*)As + wave * 2048;
    char* lB = (char*)Bs + wave * 2048;

    f32x4 acc[4][4] = {};
    for (int kb = 0; kb < K * 2; kb += 64) {
        glds16(gA0 + kb, lA);
        glds16(gA1 + kb, lA + 1024);
        glds16(gB0 + kb, lB);
        glds16(gB1 + kb, lB + 1024);
        __syncthreads();
        f16x8 fa[4], fb[4];
#pragma unroll
        for (int u = 0; u < 4; ++u) {
            fa[u] = *(const f16x8*)&As[(wm + u * 16 + col) * 32 + quad * 8];
            fb[u] = *(const f16x8*)&Bs[(wn + u * 16 + col) * 32 + quad * 8];
        }
#pragma unroll
        for (int u = 0; u < 4; ++u)
#pragma unroll
            for (int v = 0; v < 4; ++v)
                acc[u][v] = __builtin_amdgcn_mfma_f32_16x16x32_f16(fa[u], fb[v], acc[u][v], 0, 0, 0);
        __syncthreads();
    }
#pragma unroll
    for (int u = 0; u < 4; ++u)
#pragma unroll
        for (int v = 0; v < 4; ++v)
#pragma unroll
            for (int r = 0; r < 4; ++r)
                C[(size_t)(m0 + wm + u * 16 + quad * 4 + r) * 1024 + n0 + wn + v * 16 + col] =
                    acc[u][v][r];
}

// ---------------------------------------------------------------------------
extern "C" void kernel_launch(void* const* d_in, const int* in_sizes, int n_in,
                              void* d_out, int out_size, void* d_ws, size_t ws_size,
                              hipStream_t stream) {
    const float* n1 = (const float*)d_in[0];
    const float* n2 = (const float*)d_in[1];
    const float* Wc = (const float*)d_in[2];
    float* out = (float*)d_out;
    char* ws = (char*)d_ws;

    f16* n2t = (f16*)(ws);                  // [0,16M)   prep -> gemm2
    f16* Xt  = (f16*)(ws + (16u << 20));    // [16,32M)  gemm1 -> gemm2
    f16* Wf  = (f16*)(ws + (32u << 20));    // [32,34M)  prep -> gemm1 (dead before E)
    f16* E   = (f16*)(ws + (32u << 20));    // [32,64M)  gemm2 -> tr_scale
    f16* n1f = (f16*)(ws + (64u << 20));    // [64,80M)  prep -> gemm1
    f16* n2f = (f16*)(ws + (80u << 20));    // [80,96M)  prep -> gemm3
    float* Mg = (float*)(ws + (64u << 20)); // [64M,+64K)  stats (over dead n1f)
    float* Si = (float*)(ws + (64u << 20) + (1u << 16));  // +64K
    f16* At  = (f16*)(ws);                  // [0,32M)   tr_scale -> gemm3

    dim3 blk(256);
    prep<<<6656, blk, 0, stream>>>(n1, Wc, n2, n1f, Wf, n2f, n2t);
    gemm1_nt_xt<<<512, blk, 0, stream>>>(n1f, Wf, Xt);
    gemm2_nt_e<<<1024, blk, 0, stream>>>(Xt, n2t, E);
    softmax_stats<<<4096, blk, 0, stream>>>(E, Mg, Si);
    tr_scale<<<dim3(16, 16, 16), blk, 0, stream>>>(E, Mg, Si, At);
    gemm3_nt_out<<<512, blk, 0, stream>>>(n2f, At, out);
}

// Round 6
// 213.838 us; speedup vs baseline: 4.6612x; 1.0175x over previous
//
#include <hip/hip_runtime.h>
#include <math.h>

// B=16, C=512, HW=1024.  Chain (per batch):
//   X  (C x HW)  = n1 @ W_c^T
//   E  (HW x HW) = X^T @ n2
//   A  = row-softmax(E)
//   out(C x HW)  = n2 @ A
//
// Round 6: GEMMs move from 256-thread (4-wave) to 512-thread (8-wave) blocks
// on the same 128x128/BK=32/glds16 structure. Round-3 counters showed
// OccupancyPercent=18% (2 blocks/CU = 8 waves/CU): the vmcnt(0)+barrier drain
// was exposed with only 2 waves/SIMD. 8-wave blocks double resident waves
// (gemm2 reaches 32 waves/CU) so other waves cover the drain (m114 overlap).
// Wave-tile is 64x32 (acc 4x2). XCD-swizzled 1D grids kept from round 5.
//
// Workspace (96 MiB, lifetime-aliased):
//   [0,16M):   n2t  f16 (prep -> gemm2)      } At [0,32M) after gemm2
//   [16,32M):  Xt   f16 (gemm1 -> gemm2)     }
//   [32,34M):  Wf   f16 (prep -> gemm1; overlays E, written later)
//   [32,64M):  E    f16 (gemm2 -> tr_scale)
//   [64,80M):  n1f  f16 (prep -> gemm1); stats Mg/Si overlay afterwards
//   [80,96M):  n2f  f16 (prep -> gemm3)

typedef _Float16 f16;
typedef _Float16 f16x8 __attribute__((ext_vector_type(8)));
typedef _Float16 f16x4 __attribute__((ext_vector_type(4)));
typedef float f32x4 __attribute__((ext_vector_type(4)));

__device__ __forceinline__ void glds16(const void* g, void* l) {
    __builtin_amdgcn_global_load_lds((const __attribute__((address_space(1))) void*)g,
                                     (__attribute__((address_space(3))) void*)l, 16, 0, 0);
}

// ---------------------------------------------------------------------------
// Fused pre-pass (unchanged). blockIdx.x:
//   [0,4096):    n1 -> n1f     [4096,4608): Wc -> Wf
//   [4608,6656): n2 -> n2f (natural) + n2t (transposed)
__global__ __launch_bounds__(256) void prep(const float* __restrict__ n1,
                                            const float* __restrict__ Wc,
                                            const float* __restrict__ n2,
                                            f16* __restrict__ n1f, f16* __restrict__ Wf,
                                            f16* __restrict__ n2f, f16* __restrict__ n2t) {
    const int bid = blockIdx.x, tid = threadIdx.x;
    if (bid < 4608) {
        const float* s = (bid < 4096) ? n1 : Wc;
        f16* d = (bid < 4096) ? n1f : Wf;
        const size_t i = ((size_t)(bid < 4096 ? bid : bid - 4096) * 256 + tid) * 8;
        f32x4 a = *(const f32x4*)(s + i);
        f32x4 b = *(const f32x4*)(s + i + 4);
        f16x8 o;
        o[0] = (f16)a[0]; o[1] = (f16)a[1]; o[2] = (f16)a[2]; o[3] = (f16)a[3];
        o[4] = (f16)b[0]; o[5] = (f16)b[1]; o[6] = (f16)b[2]; o[7] = (f16)b[3];
        *(f16x8*)(d + i) = o;
        return;
    }
    const int id = bid - 4608;
    const int b = id >> 7;
    const int ry = (id & 127) >> 4;
    const int cx = id & 15;
    const float* S = n2 + (size_t)b * 512 * 1024;
    f16* Dn = n2f + (size_t)b * 512 * 1024;
    f16* Dt = n2t + (size_t)b * 1024 * 512;
    __shared__ f16 Ts[64 * 72];
    const int r0 = ry * 64, c0 = cx * 64;
    const int rr = tid >> 3, cc8 = (tid & 7) * 8;
#pragma unroll
    for (int h = 0; h < 2; ++h) {
        const int row = r0 + rr + 32 * h;
        const float* s = S + (size_t)row * 1024 + c0 + cc8;
        f32x4 a = *(const f32x4*)s, bq = *(const f32x4*)(s + 4);
        f16x8 o;
        o[0] = (f16)a[0]; o[1] = (f16)a[1]; o[2] = (f16)a[2]; o[3] = (f16)a[3];
        o[4] = (f16)bq[0]; o[5] = (f16)bq[1]; o[6] = (f16)bq[2]; o[7] = (f16)bq[3];
        *(f16x8*)&Ts[(rr + 32 * h) * 72 + cc8] = o;
        *(f16x8*)(Dn + (size_t)row * 1024 + c0 + cc8) = o;
    }
    __syncthreads();
    const int j = tid >> 2, k16 = (tid & 3) * 16;
    f16* d = Dt + (size_t)(c0 + j) * 512 + r0 + k16;
    f16x8 o0, o1;
#pragma unroll
    for (int i = 0; i < 8; ++i) {
        o0[i] = Ts[(k16 + i) * 72 + j];
        o1[i] = Ts[(k16 + 8 + i) * 72 + j];
    }
    *(f16x8*)d = o0;
    *(f16x8*)(d + 8) = o1;
}

// ---------------------------------------------------------------------------
// Row stats (unchanged): per-row max m and 1/sum of exp(x-m). One wave/row.
__global__ __launch_bounds__(256) void softmax_stats(const f16* __restrict__ E,
                                                     float* __restrict__ Mg,
                                                     float* __restrict__ Si) {
    const int wave = threadIdx.x >> 6, lane = threadIdx.x & 63;
    const int row = blockIdx.x * 4 + wave;
    const f16* p = E + (size_t)row * 1024 + lane * 16;
    f16x8 a = *(const f16x8*)p, b = *(const f16x8*)(p + 8);
    float v[16];
#pragma unroll
    for (int i = 0; i < 8; ++i) { v[i] = (float)a[i]; v[i + 8] = (float)b[i]; }
    float m = v[0];
#pragma unroll
    for (int i = 1; i < 16; ++i) m = fmaxf(m, v[i]);
#pragma unroll
    for (int off = 1; off < 64; off <<= 1) m = fmaxf(m, __shfl_xor(m, off, 64));
    float s = 0.f;
#pragma unroll
    for (int i = 0; i < 16; ++i) s += __expf(v[i] - m);
#pragma unroll
    for (int off = 1; off < 64; off <<= 1) s += __shfl_xor(s, off, 64);
    if (lane == 0) { Mg[row] = m; Si[row] = 1.0f / s; }
}

// ---------------------------------------------------------------------------
// At[b][j][k] = exp(E[b][k][j] - m_k) * si_k   (scaled transpose, unchanged)
__global__ __launch_bounds__(256) void tr_scale(const f16* __restrict__ S,
                                                const float* __restrict__ Mg,
                                                const float* __restrict__ Si,
                                                f16* __restrict__ D) {
    const int b = blockIdx.z;
    S += (size_t)b * 1024 * 1024;
    D += (size_t)b * 1024 * 1024;
    __shared__ f16 Ts[64 * 72];
    const int r0 = blockIdx.y * 64, c0 = blockIdx.x * 64;
    const int tid = threadIdx.x;
    const int rr = tid >> 3, cc8 = (tid & 7) * 8;
#pragma unroll
    for (int h = 0; h < 2; ++h) {
        const int row = r0 + rr + 32 * h;
        const float mg = Mg[b * 1024 + row];
        const float si = Si[b * 1024 + row];
        f16x8 v = *(const f16x8*)(S + (size_t)row * 1024 + c0 + cc8);
        f16x8 o;
#pragma unroll
        for (int i = 0; i < 8; ++i) o[i] = (f16)(__expf((float)v[i] - mg) * si);
        *(f16x8*)&Ts[(rr + 32 * h) * 72 + cc8] = o;
    }
    __syncthreads();
    const int j = tid >> 2, k16 = (tid & 3) * 16;
    f16* d = D + (size_t)(c0 + j) * 1024 + r0 + k16;
    f16x8 o0, o1;
#pragma unroll
    for (int i = 0; i < 8; ++i) {
        o0[i] = Ts[(k16 + i) * 72 + j];
        o1[i] = Ts[(k16 + 8 + i) * 72 + j];
    }
    *(f16x8*)d = o0;
    *(f16x8*)(d + 8) = o1;
}

// ---------------------------------------------------------------------------
// GEMM1: Xt[b][o][c] = (n1f[b] @ Wf^T)^T.  M=512, N=1024, K=1024.
// 512 threads (8 waves), 128x128 tile, wave-tile 64x32. Grid 512, XCD swizzle.
__global__ __launch_bounds__(512) void gemm1_nt_xt(const f16* __restrict__ A,
                                                   const f16* __restrict__ Bw,
                                                   f16* __restrict__ Xt) {
    const int M = 512, K = 1024;
    const int id = blockIdx.x;
    const int xcd = id & 7, loc = id >> 3;
    const int b = xcd * 2 + (loc >> 5);
    const int m0 = ((loc >> 3) & 3) * 128;
    const int n0 = (loc & 7) * 128;
    A += (size_t)b * M * K;
    Xt += (size_t)b * 1024 * M;
    __shared__ __attribute__((aligned(16))) f16 SM[128 * 136];  // K-loop uses 16KB; epilogue 34.8KB
    f16* As = SM;
    f16* Bs = SM + 4096;
    const int tid = threadIdx.x, lane = tid & 63, wave = tid >> 6;
    const int col = lane & 15, quad = lane >> 4;
    const int wm = (wave & 1) * 64, wn = (wave >> 1) * 32;
    const int off = wave * 1024 + lane * 16;  // byte offset in 8KB tile
    const char* gA = (const char*)(A + (size_t)(m0 + (off >> 6)) * K) + (off & 63);
    const char* gB = (const char*)(Bw + (size_t)(n0 + (off >> 6)) * K) + (off & 63);
    char* lA = (char*)As + wave * 1024;
    char* lB = (char*)Bs + wave * 1024;

    f32x4 acc[4][2] = {};
    for (int kb = 0; kb < K * 2; kb += 64) {
        glds16(gA + kb, lA);
        glds16(gB + kb, lB);
        __syncthreads();
        f16x8 fa[4], fb[2];
#pragma unroll
        for (int u = 0; u < 4; ++u) fa[u] = *(const f16x8*)&As[(wm + u * 16 + col) * 32 + quad * 8];
#pragma unroll
        for (int v = 0; v < 2; ++v) fb[v] = *(const f16x8*)&Bs[(wn + v * 16 + col) * 32 + quad * 8];
#pragma unroll
        for (int u = 0; u < 4; ++u)
#pragma unroll
            for (int v = 0; v < 2; ++v)
                acc[u][v] = __builtin_amdgcn_mfma_f32_16x16x32_f16(fa[u], fb[v], acc[u][v], 0, 0, 0);
        __syncthreads();
    }
    // Transposed epilogue via LDS: Tt[n][m] (pad 136), then coalesced Xt rows.
    f16* Tt = SM;
#pragma unroll
    for (int u = 0; u < 4; ++u)
#pragma unroll
        for (int v = 0; v < 2; ++v) {
            f16x4 p;
#pragma unroll
            for (int r = 0; r < 4; ++r) p[r] = (f16)acc[u][v][r];
            *(f16x4*)&Tt[(wn + v * 16 + col) * 136 + wm + u * 16 + quad * 4] = p;
        }
    __syncthreads();
    const int j = tid >> 2, seg = (tid & 3) * 32;
    f16* dst = Xt + (size_t)(n0 + j) * M + m0 + seg;
#pragma unroll
    for (int c8 = 0; c8 < 32; c8 += 8)
        *(f16x8*)(dst + c8) = *(const f16x8*)&Tt[j * 136 + seg + c8];
}

// ---------------------------------------------------------------------------
// GEMM2: E[b][o][h] (f16) = Xt[b] @ n2t[b]^T.  M=N=1024, K=512.
// 512 threads, grid 1024 (4 blocks/CU -> 32 waves/CU), XCD swizzle.
__global__ __launch_bounds__(512) void gemm2_nt_e(const f16* __restrict__ A,
                                                  const f16* __restrict__ B,
                                                  f16* __restrict__ E) {
    const int K = 512;
    const int id = blockIdx.x;
    const int xcd = id & 7, loc = id >> 3;
    const int b = xcd * 2 + (loc >> 6);
    const int m0 = ((loc >> 3) & 7) * 128;
    const int n0 = (loc & 7) * 128;
    A += (size_t)b * 1024 * K;
    B += (size_t)b * 1024 * K;
    E += (size_t)b * 1024 * 1024;
    __shared__ __attribute__((aligned(16))) f16 As[128 * 32], Bs[128 * 32];
    const int tid = threadIdx.x, lane = tid & 63, wave = tid >> 6;
    const int col = lane & 15, quad = lane >> 4;
    const int wm = (wave & 1) * 64, wn = (wave >> 1) * 32;
    const int off = wave * 1024 + lane * 16;
    const char* gA = (const char*)(A + (size_t)(m0 + (off >> 6)) * K) + (off & 63);
    const char* gB = (const char*)(B + (size_t)(n0 + (off >> 6)) * K) + (off & 63);
    char* lA = (char*)As + wave * 1024;
    char* lB = (char*)Bs + wave * 1024;

    f32x4 acc[4][2] = {};
    for (int kb = 0; kb < K * 2; kb += 64) {
        glds16(gA + kb, lA);
        glds16(gB + kb, lB);
        __syncthreads();
        f16x8 fa[4], fb[2];
#pragma unroll
        for (int u = 0; u < 4; ++u) fa[u] = *(const f16x8*)&As[(wm + u * 16 + col) * 32 + quad * 8];
#pragma unroll
        for (int v = 0; v < 2; ++v) fb[v] = *(const f16x8*)&Bs[(wn + v * 16 + col) * 32 + quad * 8];
#pragma unroll
        for (int u = 0; u < 4; ++u)
#pragma unroll
            for (int v = 0; v < 2; ++v)
                acc[u][v] = __builtin_amdgcn_mfma_f32_16x16x32_f16(fa[u], fb[v], acc[u][v], 0, 0, 0);
        __syncthreads();
    }
#pragma unroll
    for (int u = 0; u < 4; ++u)
#pragma unroll
        for (int v = 0; v < 2; ++v)
#pragma unroll
            for (int r = 0; r < 4; ++r)
                E[(size_t)(m0 + wm + u * 16 + quad * 4 + r) * 1024 + n0 + wn + v * 16 + col] =
                    (f16)acc[u][v][r];
}

// ---------------------------------------------------------------------------
// GEMM3: out[b][c][j] (f32) = n2f[b](f16) @ At[b]^T.  M=512, N=1024, K=1024.
// 512 threads, grid 512, XCD swizzle.
__global__ __launch_bounds__(512) void gemm3_nt_out(const f16* __restrict__ A,
                                                    const f16* __restrict__ Bt,
                                                    float* __restrict__ C) {
    const int K = 1024;
    const int id = blockIdx.x;
    const int xcd = id & 7, loc = id >> 3;
    const int b = xcd * 2 + (loc >> 5);
    const int m0 = ((loc >> 3) & 3) * 128;
    const int n0 = (loc & 7) * 128;
    A += (size_t)b * 512 * K;
    Bt += (size_t)b * 1024 * K;
    C += (size_t)b * 512 * 1024;
    __shared__ __attribute__((aligned(16))) f16 As[128 * 32], Bs[128 * 32];
    const int tid = threadIdx.x, lane = tid & 63, wave = tid >> 6;
    const int col = lane & 15, quad = lane >> 4;
    const int wm = (wave & 1) * 64, wn = (wave >> 1) * 32;
    const int off = wave * 1024 + lane * 16;
    const char* gA = (const char*)(A + (size_t)(m0 + (off >> 6)) * K) + (off & 63);
    const char* gB = (const char*)(Bt + (size_t)(n0 + (off >> 6)) * K) + (off & 63);
    char* lA = (char*)As + wave * 1024;
    char* lB = (char*)Bs + wave * 1024;

    f32x4 acc[4][2] = {};
    for (int kb = 0; kb < K * 2; kb += 64) {
        glds16(gA + kb, lA);
        glds16(gB + kb, lB);
        __syncthreads();
        f16x8 fa[4], fb[2];
#pragma unroll
        for (int u = 0; u < 4; ++u) fa[u] = *(const f16x8*)&As[(wm + u * 16 + col) * 32 + quad * 8];
#pragma unroll
        for (int v = 0; v < 2; ++v) fb[v] = *(const f16x8*)&Bs[(wn + v * 16 + col) * 32 + quad * 8];
#pragma unroll
        for (int u = 0; u < 4; ++u)
#pragma unroll
            for (int v = 0; v < 2; ++v)
                acc[u][v] = __builtin_amdgcn_mfma_f32_16x16x32_f16(fa[u], fb[v], acc[u][v], 0, 0, 0);
        __syncthreads();
    }
#pragma unroll
    for (int u = 0; u < 4; ++u)
#pragma unroll
        for (int v = 0; v < 2; ++v)
#pragma unroll
            for (int r = 0; r < 4; ++r)
                C[(size_t)(m0 + wm + u * 16 + quad * 4 + r) * 1024 + n0 + wn + v * 16 + col] =
                    acc[u][v][r];
}

// ---------------------------------------------------------------------------
extern "C" void kernel_launch(void* const* d_in, const int* in_sizes, int n_in,
                              void* d_out, int out_size, void* d_ws, size_t ws_size,
                              hipStream_t stream) {
    const float* n1 = (const float*)d_in[0];
    const float* n2 = (const float*)d_in[1];
    const float* Wc = (const float*)d_in[2];
    float* out = (float*)d_out;
    char* ws = (char*)d_ws;

    f16* n2t = (f16*)(ws);                  // [0,16M)   prep -> gemm2
    f16* Xt  = (f16*)(ws + (16u << 20));    // [16,32M)  gemm1 -> gemm2
    f16* Wf  = (f16*)(ws + (32u << 20));    // [32,34M)  prep -> gemm1 (dead before E)
    f16* E   = (f16*)(ws + (32u << 20));    // [32,64M)  gemm2 -> tr_scale
    f16* n1f = (f16*)(ws + (64u << 20));    // [64,80M)  prep -> gemm1
    f16* n2f = (f16*)(ws + (80u << 20));    // [80,96M)  prep -> gemm3
    float* Mg = (float*)(ws + (64u << 20)); // stats over dead n1f
    float* Si = (float*)(ws + (64u << 20) + (1u << 16));
    f16* At  = (f16*)(ws);                  // [0,32M)   tr_scale -> gemm3

    prep<<<6656, dim3(256), 0, stream>>>(n1, Wc, n2, n1f, Wf, n2f, n2t);
    gemm1_nt_xt<<<512, dim3(512), 0, stream>>>(n1f, Wf, Xt);
    gemm2_nt_e<<<1024, dim3(512), 0, stream>>>(Xt, n2t, E);
    softmax_stats<<<4096, dim3(256), 0, stream>>>(E, Mg, Si);
    tr_scale<<<dim3(16, 16, 16), dim3(256), 0, stream>>>(E, Mg, Si, At);
    gemm3_nt_out<<<512, dim3(512), 0, stream>>>(n2f, At, out);
}

// Round 7
// 203.595 us; speedup vs baseline: 4.8957x; 1.0503x over previous
//
#include <hip/hip_runtime.h>
#include <math.h>

// B=16, C=512, HW=1024.  Chain (per batch):
//   X  (C x HW)  = n1 @ W_c^T
//   E  (HW x HW) = X^T @ n2
//   A  = row-softmax(E)
//   out(C x HW)  = n2 @ A
//
// Round 7: K-loop restructured. global_load_lds + __syncthreads forced a
// vmcnt(0) drain every K-step (the m97 structural stall — measured ~2/3 of
// step time here). New K-loop: global->VGPR prefetch, ds_write_b128 into a
// double-buffered LDS tile, ONE raw barrier per step:
//     asm("s_waitcnt lgkmcnt(0); s_barrier")
// No workgroup fence => compiler emits fine-grained vmcnt(N) only where the
// ds_write consumes prefetched regs; loads stay in flight across the barrier.
// 512-thread blocks, 128x128 tile, BK=32, wave-tile 64x32, XCD swizzle kept.
//
// Workspace (96 MiB, lifetime-aliased):
//   [0,16M):   n2t  f16 (prep -> gemm2)      } At [0,32M) after gemm2
//   [16,32M):  Xt   f16 (gemm1 -> gemm2)     }
//   [32,34M):  Wf   f16 (prep -> gemm1; overlays E, written later)
//   [32,64M):  E    f16 (gemm2 -> tr_scale)
//   [64,80M):  n1f  f16 (prep -> gemm1); stats Mg/Si overlay afterwards
//   [80,96M):  n2f  f16 (prep -> gemm3)

typedef _Float16 f16;
typedef _Float16 f16x8 __attribute__((ext_vector_type(8)));
typedef _Float16 f16x4 __attribute__((ext_vector_type(4)));
typedef float f32x4 __attribute__((ext_vector_type(4)));

// Barrier with LDS-drain only (no vmcnt drain): prefetch survives it.
#define WG_BARRIER() asm volatile("s_waitcnt lgkmcnt(0)\ns_barrier" ::: "memory")

// ---------------------------------------------------------------------------
// Fused pre-pass (unchanged). blockIdx.x:
//   [0,4096):    n1 -> n1f     [4096,4608): Wc -> Wf
//   [4608,6656): n2 -> n2f (natural) + n2t (transposed)
__global__ __launch_bounds__(256) void prep(const float* __restrict__ n1,
                                            const float* __restrict__ Wc,
                                            const float* __restrict__ n2,
                                            f16* __restrict__ n1f, f16* __restrict__ Wf,
                                            f16* __restrict__ n2f, f16* __restrict__ n2t) {
    const int bid = blockIdx.x, tid = threadIdx.x;
    if (bid < 4608) {
        const float* s = (bid < 4096) ? n1 : Wc;
        f16* d = (bid < 4096) ? n1f : Wf;
        const size_t i = ((size_t)(bid < 4096 ? bid : bid - 4096) * 256 + tid) * 8;
        f32x4 a = *(const f32x4*)(s + i);
        f32x4 b = *(const f32x4*)(s + i + 4);
        f16x8 o;
        o[0] = (f16)a[0]; o[1] = (f16)a[1]; o[2] = (f16)a[2]; o[3] = (f16)a[3];
        o[4] = (f16)b[0]; o[5] = (f16)b[1]; o[6] = (f16)b[2]; o[7] = (f16)b[3];
        *(f16x8*)(d + i) = o;
        return;
    }
    const int id = bid - 4608;
    const int b = id >> 7;
    const int ry = (id & 127) >> 4;
    const int cx = id & 15;
    const float* S = n2 + (size_t)b * 512 * 1024;
    f16* Dn = n2f + (size_t)b * 512 * 1024;
    f16* Dt = n2t + (size_t)b * 1024 * 512;
    __shared__ f16 Ts[64 * 72];
    const int r0 = ry * 64, c0 = cx * 64;
    const int rr = tid >> 3, cc8 = (tid & 7) * 8;
#pragma unroll
    for (int h = 0; h < 2; ++h) {
        const int row = r0 + rr + 32 * h;
        const float* s = S + (size_t)row * 1024 + c0 + cc8;
        f32x4 a = *(const f32x4*)s, bq = *(const f32x4*)(s + 4);
        f16x8 o;
        o[0] = (f16)a[0]; o[1] = (f16)a[1]; o[2] = (f16)a[2]; o[3] = (f16)a[3];
        o[4] = (f16)bq[0]; o[5] = (f16)bq[1]; o[6] = (f16)bq[2]; o[7] = (f16)bq[3];
        *(f16x8*)&Ts[(rr + 32 * h) * 72 + cc8] = o;
        *(f16x8*)(Dn + (size_t)row * 1024 + c0 + cc8) = o;
    }
    __syncthreads();
    const int j = tid >> 2, k16 = (tid & 3) * 16;
    f16* d = Dt + (size_t)(c0 + j) * 512 + r0 + k16;
    f16x8 o0, o1;
#pragma unroll
    for (int i = 0; i < 8; ++i) {
        o0[i] = Ts[(k16 + i) * 72 + j];
        o1[i] = Ts[(k16 + 8 + i) * 72 + j];
    }
    *(f16x8*)d = o0;
    *(f16x8*)(d + 8) = o1;
}

// ---------------------------------------------------------------------------
// Row stats (unchanged): per-row max m and 1/sum of exp(x-m). One wave/row.
__global__ __launch_bounds__(256) void softmax_stats(const f16* __restrict__ E,
                                                     float* __restrict__ Mg,
                                                     float* __restrict__ Si) {
    const int wave = threadIdx.x >> 6, lane = threadIdx.x & 63;
    const int row = blockIdx.x * 4 + wave;
    const f16* p = E + (size_t)row * 1024 + lane * 16;
    f16x8 a = *(const f16x8*)p, b = *(const f16x8*)(p + 8);
    float v[16];
#pragma unroll
    for (int i = 0; i < 8; ++i) { v[i] = (float)a[i]; v[i + 8] = (float)b[i]; }
    float m = v[0];
#pragma unroll
    for (int i = 1; i < 16; ++i) m = fmaxf(m, v[i]);
#pragma unroll
    for (int off = 1; off < 64; off <<= 1) m = fmaxf(m, __shfl_xor(m, off, 64));
    float s = 0.f;
#pragma unroll
    for (int i = 0; i < 16; ++i) s += __expf(v[i] - m);
#pragma unroll
    for (int off = 1; off < 64; off <<= 1) s += __shfl_xor(s, off, 64);
    if (lane == 0) { Mg[row] = m; Si[row] = 1.0f / s; }
}

// ---------------------------------------------------------------------------
// At[b][j][k] = exp(E[b][k][j] - m_k) * si_k   (scaled transpose, unchanged)
__global__ __launch_bounds__(256) void tr_scale(const f16* __restrict__ S,
                                                const float* __restrict__ Mg,
                                                const float* __restrict__ Si,
                                                f16* __restrict__ D) {
    const int b = blockIdx.z;
    S += (size_t)b * 1024 * 1024;
    D += (size_t)b * 1024 * 1024;
    __shared__ f16 Ts[64 * 72];
    const int r0 = blockIdx.y * 64, c0 = blockIdx.x * 64;
    const int tid = threadIdx.x;
    const int rr = tid >> 3, cc8 = (tid & 7) * 8;
#pragma unroll
    for (int h = 0; h < 2; ++h) {
        const int row = r0 + rr + 32 * h;
        const float mg = Mg[b * 1024 + row];
        const float si = Si[b * 1024 + row];
        f16x8 v = *(const f16x8*)(S + (size_t)row * 1024 + c0 + cc8);
        f16x8 o;
#pragma unroll
        for (int i = 0; i < 8; ++i) o[i] = (f16)(__expf((float)v[i] - mg) * si);
        *(f16x8*)&Ts[(rr + 32 * h) * 72 + cc8] = o;
    }
    __syncthreads();
    const int j = tid >> 2, k16 = (tid & 3) * 16;
    f16* d = D + (size_t)(c0 + j) * 1024 + r0 + k16;
    f16x8 o0, o1;
#pragma unroll
    for (int i = 0; i < 8; ++i) {
        o0[i] = Ts[(k16 + i) * 72 + j];
        o1[i] = Ts[(k16 + 8 + i) * 72 + j];
    }
    *(f16x8*)d = o0;
    *(f16x8*)(d + 8) = o1;
}

// ---------------------------------------------------------------------------
// Double-buffered K-loop core, shared by all GEMMs.
//   SM layout: A0[8K] A1[8K] B0[8K] B1[8K]  (row-major 128x32 f16 each)
//   per-thread stage slot: 16 B at off = wave*1024 + lane*16
#define GEMM_CORE(NS)                                                                   \
    f16x8 ra = *(const f16x8*)gAp, rb = *(const f16x8*)gBp;                             \
    *(f16x8*)wA0 = ra; *(f16x8*)wB0 = rb;                                               \
    ra = *(const f16x8*)(gAp + 64); rb = *(const f16x8*)(gBp + 64);                     \
    WG_BARRIER();                                                                       \
    f32x4 acc[4][2] = {};                                                               \
_Pragma("unroll")                                                                       \
    for (int kb = 0; kb < (NS); ++kb) {                                                 \
        const f16* Ac = (const f16*)(SM + (kb & 1) * 8192);                             \
        const f16* Bc = (const f16*)(SM + 16384 + (kb & 1) * 8192);                     \
        f16x8 fa[4], fb[2];                                                             \
_Pragma("unroll")                                                                       \
        for (int u = 0; u < 4; ++u)                                                     \
            fa[u] = *(const f16x8*)&Ac[(wm + u * 16 + col) * 32 + quad * 8];            \
_Pragma("unroll")                                                                       \
        for (int v = 0; v < 2; ++v)                                                     \
            fb[v] = *(const f16x8*)&Bc[(wn + v * 16 + col) * 32 + quad * 8];            \
_Pragma("unroll")                                                                       \
        for (int u = 0; u < 4; ++u)                                                     \
_Pragma("unroll")                                                                       \
            for (int v = 0; v < 2; ++v)                                                 \
                acc[u][v] = __builtin_amdgcn_mfma_f32_16x16x32_f16(fa[u], fb[v],        \
                                                                   acc[u][v], 0, 0, 0);\
        if (kb + 1 < (NS)) {                                                            \
            char* dA = SM + ((kb + 1) & 1) * 8192 + off;                                \
            char* dB = SM + 16384 + ((kb + 1) & 1) * 8192 + off;                        \
            *(f16x8*)dA = ra;                                                           \
            *(f16x8*)dB = rb;                                                           \
            if (kb + 2 < (NS)) {                                                        \
                ra = *(const f16x8*)(gAp + (size_t)(kb + 2) * 64);                      \
                rb = *(const f16x8*)(gBp + (size_t)(kb + 2) * 64);                      \
            }                                                                           \
            WG_BARRIER();                                                               \
        }                                                                               \
    }

// ---------------------------------------------------------------------------
// GEMM1: Xt[b][o][c] = (n1f[b] @ Wf^T)^T.  M=512, N=1024, K=1024.
__global__ __launch_bounds__(512) void gemm1_nt_xt(const f16* __restrict__ A,
                                                   const f16* __restrict__ Bw,
                                                   f16* __restrict__ Xt) {
    const int M = 512, K = 1024;
    const int id = blockIdx.x;
    const int xcd = id & 7, loc = id >> 3;
    const int b = xcd * 2 + (loc >> 5);
    const int m0 = ((loc >> 3) & 3) * 128;
    const int n0 = (loc & 7) * 128;
    A += (size_t)b * M * K;
    Xt += (size_t)b * 1024 * M;
    __shared__ __attribute__((aligned(16))) char SM[34816];  // 4x8K bufs; Tt epilogue 34.8K
    const int tid = threadIdx.x, lane = tid & 63, wave = tid >> 6;
    const int col = lane & 15, quad = lane >> 4;
    const int wm = (wave & 1) * 64, wn = (wave >> 1) * 32;
    const int off = wave * 1024 + lane * 16;
    const int srow = off >> 6, scolb = off & 63;
    const char* gAp = (const char*)A + (size_t)(m0 + srow) * K * 2 + scolb;
    const char* gBp = (const char*)Bw + (size_t)(n0 + srow) * K * 2 + scolb;
    char* wA0 = SM + off;
    char* wB0 = SM + 16384 + off;

    GEMM_CORE(32)

    // Transposed epilogue via LDS: Tt[n][m] (pad 136), then coalesced Xt rows.
    WG_BARRIER();  // all frag reads of SM done before overwrite
    f16* Tt = (f16*)SM;
#pragma unroll
    for (int u = 0; u < 4; ++u)
#pragma unroll
        for (int v = 0; v < 2; ++v) {
            f16x4 p;
#pragma unroll
            for (int r = 0; r < 4; ++r) p[r] = (f16)acc[u][v][r];
            *(f16x4*)&Tt[(wn + v * 16 + col) * 136 + wm + u * 16 + quad * 4] = p;
        }
    WG_BARRIER();
    const int j = tid >> 2, seg = (tid & 3) * 32;
    f16* dst = Xt + (size_t)(n0 + j) * M + m0 + seg;
#pragma unroll
    for (int c8 = 0; c8 < 32; c8 += 8)
        *(f16x8*)(dst + c8) = *(const f16x8*)&Tt[j * 136 + seg + c8];
}

// ---------------------------------------------------------------------------
// GEMM2: E[b][o][h] (f16) = Xt[b] @ n2t[b]^T.  M=N=1024, K=512.
__global__ __launch_bounds__(512) void gemm2_nt_e(const f16* __restrict__ A,
                                                  const f16* __restrict__ B,
                                                  f16* __restrict__ E) {
    const int K = 512;
    const int id = blockIdx.x;
    const int xcd = id & 7, loc = id >> 3;
    const int b = xcd * 2 + (loc >> 6);
    const int m0 = ((loc >> 3) & 7) * 128;
    const int n0 = (loc & 7) * 128;
    A += (size_t)b * 1024 * K;
    B += (size_t)b * 1024 * K;
    E += (size_t)b * 1024 * 1024;
    __shared__ __attribute__((aligned(16))) char SM[32768];
    const int tid = threadIdx.x, lane = tid & 63, wave = tid >> 6;
    const int col = lane & 15, quad = lane >> 4;
    const int wm = (wave & 1) * 64, wn = (wave >> 1) * 32;
    const int off = wave * 1024 + lane * 16;
    const int srow = off >> 6, scolb = off & 63;
    const char* gAp = (const char*)A + (size_t)(m0 + srow) * K * 2 + scolb;
    const char* gBp = (const char*)B + (size_t)(n0 + srow) * K * 2 + scolb;
    char* wA0 = SM + off;
    char* wB0 = SM + 16384 + off;

    GEMM_CORE(16)

#pragma unroll
    for (int u = 0; u < 4; ++u)
#pragma unroll
        for (int v = 0; v < 2; ++v)
#pragma unroll
            for (int r = 0; r < 4; ++r)
                E[(size_t)(m0 + wm + u * 16 + quad * 4 + r) * 1024 + n0 + wn + v * 16 + col] =
                    (f16)acc[u][v][r];
}

// ---------------------------------------------------------------------------
// GEMM3: out[b][c][j] (f32) = n2f[b](f16) @ At[b]^T.  M=512, N=1024, K=1024.
__global__ __launch_bounds__(512) void gemm3_nt_out(const f16* __restrict__ A,
                                                    const f16* __restrict__ Bt,
                                                    float* __restrict__ C) {
    const int K = 1024;
    const int id = blockIdx.x;
    const int xcd = id & 7, loc = id >> 3;
    const int b = xcd * 2 + (loc >> 5);
    const int m0 = ((loc >> 3) & 3) * 128;
    const int n0 = (loc & 7) * 128;
    A += (size_t)b * 512 * K;
    Bt += (size_t)b * 1024 * K;
    C += (size_t)b * 512 * 1024;
    __shared__ __attribute__((aligned(16))) char SM[32768];
    const int tid = threadIdx.x, lane = tid & 63, wave = tid >> 6;
    const int col = lane & 15, quad = lane >> 4;
    const int wm = (wave & 1) * 64, wn = (wave >> 1) * 32;
    const int off = wave * 1024 + lane * 16;
    const int srow = off >> 6, scolb = off & 63;
    const char* gAp = (const char*)A + (size_t)(m0 + srow) * K * 2 + scolb;
    const char* gBp = (const char*)Bt + (size_t)(n0 + srow) * K * 2 + scolb;
    char* wA0 = SM + off;
    char* wB0 = SM + 16384 + off;

    GEMM_CORE(32)

#pragma unroll
    for (int u = 0; u < 4; ++u)
#pragma unroll
        for (int v = 0; v < 2; ++v)
#pragma unroll
            for (int r = 0; r < 4; ++r)
                C[(size_t)(m0 + wm + u * 16 + quad * 4 + r) * 1024 + n0 + wn + v * 16 + col] =
                    acc[u][v][r];
}

// ---------------------------------------------------------------------------
extern "C" void kernel_launch(void* const* d_in, const int* in_sizes, int n_in,
                              void* d_out, int out_size, void* d_ws, size_t ws_size,
                              hipStream_t stream) {
    const float* n1 = (const float*)d_in[0];
    const float* n2 = (const float*)d_in[1];
    const float* Wc = (const float*)d_in[2];
    float* out = (float*)d_out;
    char* ws = (char*)d_ws;

    f16* n2t = (f16*)(ws);                  // [0,16M)   prep -> gemm2
    f16* Xt  = (f16*)(ws + (16u << 20));    // [16,32M)  gemm1 -> gemm2
    f16* Wf  = (f16*)(ws + (32u << 20));    // [32,34M)  prep -> gemm1 (dead before E)
    f16* E   = (f16*)(ws + (32u << 20));    // [32,64M)  gemm2 -> tr_scale
    f16* n1f = (f16*)(ws + (64u << 20));    // [64,80M)  prep -> gemm1
    f16* n2f = (f16*)(ws + (80u << 20));    // [80,96M)  prep -> gemm3
    float* Mg = (float*)(ws + (64u << 20)); // stats over dead n1f
    float* Si = (float*)(ws + (64u << 20) + (1u << 16));
    f16* At  = (f16*)(ws);                  // [0,32M)   tr_scale -> gemm3

    prep<<<6656, dim3(256), 0, stream>>>(n1, Wc, n2, n1f, Wf, n2f, n2t);
    gemm1_nt_xt<<<512, dim3(512), 0, stream>>>(n1f, Wf, Xt);
    gemm2_nt_e<<<1024, dim3(512), 0, stream>>>(Xt, n2t, E);
    softmax_stats<<<4096, dim3(256), 0, stream>>>(E, Mg, Si);
    tr_scale<<<dim3(16, 16, 16), dim3(256), 0, stream>>>(E, Mg, Si, At);
    gemm3_nt_out<<<512, dim3(512), 0, stream>>>(n2f, At, out);
}